// Round 4
// baseline (324.124 us; speedup 1.0000x reference)
//
#include <hip/hip_runtime.h>
#include <math.h>

#define B_ 8
#define T_ 2048
#define D_ 1024
#define H_ 128
#define BT (B_ * T_)

typedef short bf16x8 __attribute__((ext_vector_type(8)));
typedef float f32x4 __attribute__((ext_vector_type(4)));

static constexpr float SCALE = 0.08838834764831845f;  // 1/sqrt(128)

__device__ inline unsigned short f2b(float f) {
  unsigned int u = __float_as_uint(f);
  u += 0x7FFF + ((u >> 16) & 1);  // RNE
  return (unsigned short)(u >> 16);
}
__device__ inline unsigned int pk2(float a, float b) {
  return (unsigned int)f2b(a) | ((unsigned int)f2b(b) << 16);
}

// ---------------------------------------------------------------------------
// Setup: W[d][h] fp32 -> Wt[sel][h][d] bf16 (transposed). One-shot, tiny.
// ---------------------------------------------------------------------------
__global__ __launch_bounds__(256) void wcvt_kernel(
    const float* __restrict__ Wq, const float* __restrict__ Wk,
    const float* __restrict__ Wv, short* __restrict__ Wt) {
  const int sel = blockIdx.y;
  const float* W = sel == 0 ? Wq : (sel == 1 ? Wk : Wv);
  short* dst = Wt + (size_t)sel * D_ * H_;
  int slot = blockIdx.x * 256 + threadIdx.x;  // 32768 slots
  int d = slot >> 5, hg = slot & 31;
  float4 w = *(const float4*)(W + (size_t)d * H_ + hg * 4);
  dst[(size_t)(hg * 4 + 0) * D_ + d] = (short)f2b(w.x);
  dst[(size_t)(hg * 4 + 1) * D_ + d] = (short)f2b(w.y);
  dst[(size_t)(hg * 4 + 2) * D_ + d] = (short)f2b(w.z);
  dst[(size_t)(hg * 4 + 3) * D_ + d] = (short)f2b(w.w);
}

// ---------------------------------------------------------------------------
// Proj: C = X*W, bf16 MFMA, 64 rows x 128 cols per block (4 waves).
// Wave tile 32x64 (2x4 frags). Register-prefetch double buffering.
// __launch_bounds__(256,2): VGPR budget 256 so prefetch regs DON'T spill
// (round 3: bare (256) capped at 76 VGPR -> 63 MB scratch traffic).
// ---------------------------------------------------------------------------
__global__ __launch_bounds__(256, 2) void proj_kernel(
    const float* __restrict__ x, const short* __restrict__ Wt,
    short* __restrict__ qb, short* __restrict__ kb, short* __restrict__ vtb) {
  __shared__ alignas(16) char smem[27648];
  short* Xs = (short*)smem;           // [64][72] bf16
  short* Ws = (short*)(smem + 9216);  // [128][72] bf16

  const int tid = threadIdx.x;
  const int wave = tid >> 6, lane = tid & 63;
  const int ln = lane & 15, quad = lane >> 4;
  const int mw = wave & 1, nw = wave >> 1;  // wave -> 32-row, 64-col subtile
  const int sel = blockIdx.y;
  const int row0 = blockIdx.x * 64;
  const short* W = Wt + (size_t)sel * (size_t)(D_ * H_);

  f32x4 acc[2][4];
#pragma unroll
  for (int mi = 0; mi < 2; ++mi)
#pragma unroll
    for (int nt = 0; nt < 4; ++nt) acc[mi][nt] = (f32x4){0.f, 0.f, 0.f, 0.f};

  float4 xr[4];  // X prefetch: 64x64 fp32 tile, 4 float4/thread
  int4 wr[4];    // W prefetch: 128x64 bf16 tile, 4 int4/thread

#pragma unroll
  for (int i = 0; i < 4; ++i) {  // prefetch k0 = 0
    int slot = tid + i * 256;
    int r = slot >> 4, g = slot & 15;
    xr[i] = *(const float4*)(x + (size_t)(row0 + r) * D_ + g * 4);
    int n = slot >> 3, gw = slot & 7;
    wr[i] = *(const int4*)(W + (size_t)n * D_ + gw * 8);
  }

  for (int s = 0; s < 16; ++s) {
    if (s) __syncthreads();  // LDS free (prev compute done)
    // store prefetched regs -> LDS (X packed to bf16)
#pragma unroll
    for (int i = 0; i < 4; ++i) {
      int slot = tid + i * 256;
      int r = slot >> 4, g = slot & 15;
      unsigned int* p = (unsigned int*)&Xs[r * 72 + g * 4];
      p[0] = pk2(xr[i].x, xr[i].y);
      p[1] = pk2(xr[i].z, xr[i].w);
      int n = slot >> 3, gw = slot & 7;
      *(int4*)&Ws[n * 72 + gw * 8] = wr[i];
    }
    // issue next tile's loads; they complete during compute below
    if (s < 15) {
      const int k0 = (s + 1) * 64;
#pragma unroll
      for (int i = 0; i < 4; ++i) {
        int slot = tid + i * 256;
        int r = slot >> 4, g = slot & 15;
        xr[i] = *(const float4*)(x + (size_t)(row0 + r) * D_ + k0 + g * 4);
        int n = slot >> 3, gw = slot & 7;
        wr[i] = *(const int4*)(W + (size_t)n * D_ + k0 + gw * 8);
      }
    }
    __syncthreads();

#pragma unroll
    for (int kk = 0; kk < 2; ++kk) {
      bf16x8 a[2];
#pragma unroll
      for (int mi = 0; mi < 2; ++mi)
        a[mi] = *(bf16x8*)&Xs[(mw * 32 + mi * 16 + ln) * 72 + kk * 32 + quad * 8];
#pragma unroll
      for (int nt = 0; nt < 4; ++nt) {
        bf16x8 bb = *(bf16x8*)&Ws[(nw * 64 + nt * 16 + ln) * 72 + kk * 32 + quad * 8];
#pragma unroll
        for (int mi = 0; mi < 2; ++mi)
          acc[mi][nt] = __builtin_amdgcn_mfma_f32_16x16x32_bf16(a[mi], bb, acc[mi][nt], 0, 0, 0);
      }
    }
  }

  __syncthreads();  // done with Xs/Ws; reuse smem for epilogue repack
  short* Cs = (short*)smem;
  if (sel < 2) {
    short* out = sel ? kb : qb;
    // frags -> Cs[64][136] row-major (17.4 KB, fits)
#pragma unroll
    for (int mi = 0; mi < 2; ++mi)
#pragma unroll
      for (int nt = 0; nt < 4; ++nt)
#pragma unroll
        for (int rr = 0; rr < 4; ++rr)
          Cs[(mw * 32 + mi * 16 + quad * 4 + rr) * 136 + nw * 64 + nt * 16 + ln] =
              (short)f2b(acc[mi][nt][rr]);
    __syncthreads();
#pragma unroll
    for (int i = 0; i < 4; ++i) {
      int slot = tid + i * 256;  // 1024 int4 slots = 64 rows x 16 groups
      int r = slot >> 4, g = slot & 15;
      *(int4*)(out + (size_t)(row0 + r) * H_ + g * 8) = *(int4*)&Cs[r * 136 + g * 8];
    }
  } else {
    // transpose through LDS, write vt[b][h][t] coalesced
#pragma unroll
    for (int mi = 0; mi < 2; ++mi)
#pragma unroll
      for (int nt = 0; nt < 4; ++nt)
#pragma unroll
        for (int rr = 0; rr < 4; ++rr)
          Cs[(nw * 64 + nt * 16 + ln) * 72 + mw * 32 + mi * 16 + quad * 4 + rr] =
              (short)f2b(acc[mi][nt][rr]);
    __syncthreads();
    const int b = row0 >> 11, t0 = row0 & 2047;
#pragma unroll
    for (int i = 0; i < 4; ++i) {
      int slot = tid + i * 256;  // 1024 int4 slots = 128 h x 8 groups
      int h = slot >> 3, g = slot & 7;
      *(int4*)(vtb + (size_t)(b * H_ + h) * T_ + t0 + g * 8) = *(int4*)&Cs[h * 72 + g * 8];
    }
  }
}

// ---------------------------------------------------------------------------
// Attention: flash-style MFMA, 32 queries/block, 64-key chunks, register
// prefetch for next chunk. __launch_bounds__(256,2) to prevent spill.
// ---------------------------------------------------------------------------
__global__ __launch_bounds__(256, 2) void attn_kernel(
    const short* __restrict__ qb, const short* __restrict__ kb,
    const short* __restrict__ vtb, float* __restrict__ out) {
  __shared__ alignas(16) short Ks[64 * 136];   // [64][136] (+8 pad)
  __shared__ alignas(16) short Vt[128 * 72];   // [128][72] (+8 pad)
  __shared__ alignas(16) float Sf[32 * 65];    // [32][65] f32
  __shared__ alignas(16) short P[32 * 72];     // [32][72] bf16
  __shared__ float aA[32], lL[32];

  const int tid = threadIdx.x;
  const int wave = tid >> 6, lane = tid & 63;
  const int ln = lane & 15, quad = lane >> 4;
  const int b = blockIdx.x >> 6;
  const int tile = 63 - (blockIdx.x & 63);  // heavy tiles first
  const int q0 = tile * 32;

  bf16x8 qfr[2][4];  // Q frags resident in registers
#pragma unroll
  for (int m = 0; m < 2; ++m)
#pragma unroll
    for (int kk = 0; kk < 4; ++kk)
      qfr[m][kk] = *(const bf16x8*)(qb + (size_t)(b * T_ + q0 + m * 16 + ln) * H_ +
                                    kk * 32 + quad * 8);

  f32x4 oacc[2][2];
#pragma unroll
  for (int m = 0; m < 2; ++m)
#pragma unroll
    for (int nt = 0; nt < 2; ++nt) oacc[m][nt] = (f32x4){0.f, 0.f, 0.f, 0.f};

  const int srow = tid >> 3, l8 = tid & 7;
  float m_run = -INFINITY, l_run = 0.f;

  int4 kr[4], vr[4];  // prefetch regs: 16 KB K + 16 KB V^T per chunk
#pragma unroll
  for (int i = 0; i < 4; ++i) {  // prefetch chunk 0
    int slot = tid + i * 256;
    int r = slot >> 4, g = slot & 15;
    kr[i] = *(const int4*)(kb + (size_t)(b * T_ + r) * H_ + g * 8);
    int h = slot >> 3, g2 = slot & 7;
    vr[i] = *(const int4*)(vtb + (size_t)(b * H_ + h) * T_ + g2 * 8);
  }

  const int nch = ((q0 + 31) >> 6) + 1;
  for (int ch = 0; ch < nch; ++ch) {
    const int s0 = ch * 64;
    if (ch) __syncthreads();  // prev QK^T/PV done reading Ks/Vt
#pragma unroll
    for (int i = 0; i < 4; ++i) {
      int slot = tid + i * 256;
      int r = slot >> 4, g = slot & 15;
      *(int4*)&Ks[r * 136 + g * 8] = kr[i];
      int h = slot >> 3, g2 = slot & 7;
      *(int4*)&Vt[h * 72 + g2 * 8] = vr[i];
    }
    if (ch + 1 < nch) {  // issue next chunk's loads; fly during compute
      const int sn = s0 + 64;
#pragma unroll
      for (int i = 0; i < 4; ++i) {
        int slot = tid + i * 256;
        int r = slot >> 4, g = slot & 15;
        kr[i] = *(const int4*)(kb + (size_t)(b * T_ + sn + r) * H_ + g * 8);
        int h = slot >> 3, g2 = slot & 7;
        vr[i] = *(const int4*)(vtb + (size_t)(b * H_ + h) * T_ + sn + g2 * 8);
      }
    }
    __syncthreads();

    // S = Q K^T : each wave 32 queries x 16 keys
    f32x4 sacc[2];
    sacc[0] = (f32x4){0.f, 0.f, 0.f, 0.f};
    sacc[1] = (f32x4){0.f, 0.f, 0.f, 0.f};
#pragma unroll
    for (int kk = 0; kk < 4; ++kk) {
      bf16x8 bk = *(bf16x8*)&Ks[(wave * 16 + ln) * 136 + kk * 32 + quad * 8];
#pragma unroll
      for (int m = 0; m < 2; ++m)
        sacc[m] = __builtin_amdgcn_mfma_f32_16x16x32_bf16(qfr[m][kk], bk, sacc[m], 0, 0, 0);
    }
#pragma unroll
    for (int m = 0; m < 2; ++m)
#pragma unroll
      for (int r = 0; r < 4; ++r)
        Sf[(m * 16 + quad * 4 + r) * 65 + wave * 16 + ln] = sacc[m][r];
    __syncthreads();

    // online softmax: 8 lanes per row
    float sv[8];
    const int qg = q0 + srow;
#pragma unroll
    for (int i = 0; i < 8; ++i) {
      float s = Sf[srow * 65 + l8 * 8 + i] * SCALE;
      sv[i] = (s0 + l8 * 8 + i <= qg) ? s : -INFINITY;
    }
    float mx = sv[0];
#pragma unroll
    for (int i = 1; i < 8; ++i) mx = fmaxf(mx, sv[i]);
    mx = fmaxf(mx, __shfl_xor(mx, 1));
    mx = fmaxf(mx, __shfl_xor(mx, 2));
    mx = fmaxf(mx, __shfl_xor(mx, 4));
    const float mnew = fmaxf(m_run, mx);
    const float alpha = __expf(m_run - mnew);
    float p[8], ps = 0.f;
#pragma unroll
    for (int i = 0; i < 8; ++i) {
      p[i] = __expf(sv[i] - mnew);
      ps += p[i];
    }
    ps += __shfl_xor(ps, 1);
    ps += __shfl_xor(ps, 2);
    ps += __shfl_xor(ps, 4);
    l_run = l_run * alpha + ps;
    m_run = mnew;
    int4 pw;
    pw.x = (int)pk2(p[0], p[1]);
    pw.y = (int)pk2(p[2], p[3]);
    pw.z = (int)pk2(p[4], p[5]);
    pw.w = (int)pk2(p[6], p[7]);
    *(int4*)&P[srow * 72 + l8 * 8] = pw;
    if (l8 == 0) aA[srow] = alpha;
    __syncthreads();

    // O = O*alpha + P V : each wave 32 queries x 32 head-dims
    const int h0 = wave * 32;
    float ar[2][4];
#pragma unroll
    for (int m = 0; m < 2; ++m)
#pragma unroll
      for (int r = 0; r < 4; ++r) ar[m][r] = aA[m * 16 + quad * 4 + r];
#pragma unroll
    for (int m = 0; m < 2; ++m)
#pragma unroll
      for (int nt = 0; nt < 2; ++nt)
#pragma unroll
        for (int r = 0; r < 4; ++r) oacc[m][nt][r] *= ar[m][r];
#pragma unroll
    for (int ks = 0; ks < 2; ++ks) {
      bf16x8 pa[2];
      pa[0] = *(bf16x8*)&P[ln * 72 + ks * 32 + quad * 8];
      pa[1] = *(bf16x8*)&P[(16 + ln) * 72 + ks * 32 + quad * 8];
#pragma unroll
      for (int nt = 0; nt < 2; ++nt) {
        bf16x8 bv = *(bf16x8*)&Vt[(h0 + nt * 16 + ln) * 72 + ks * 32 + quad * 8];
#pragma unroll
        for (int m = 0; m < 2; ++m)
          oacc[m][nt] = __builtin_amdgcn_mfma_f32_16x16x32_bf16(pa[m], bv, oacc[m][nt], 0, 0, 0);
      }
    }
  }

  if (l8 == 0) lL[srow] = l_run;
  __syncthreads();
  const int h0 = wave * 32;
#pragma unroll
  for (int m = 0; m < 2; ++m) {
    float linv[4];
#pragma unroll
    for (int r = 0; r < 4; ++r) linv[r] = 1.f / lL[m * 16 + quad * 4 + r];
#pragma unroll
    for (int nt = 0; nt < 2; ++nt)
#pragma unroll
      for (int r = 0; r < 4; ++r) {
        int row = q0 + m * 16 + quad * 4 + r;
        out[(size_t)(b * T_ + row) * H_ + h0 + nt * 16 + ln] = oacc[m][nt][r] * linv[r];
      }
  }
}

// ---------------------------------------------------------------------------
extern "C" void kernel_launch(void* const* d_in, const int* in_sizes, int n_in,
                              void* d_out, int out_size, void* d_ws, size_t ws_size,
                              hipStream_t stream) {
  const float* x  = (const float*)d_in[0];
  const float* Wq = (const float*)d_in[1];
  const float* Wk = (const float*)d_in[2];
  const float* Wv = (const float*)d_in[3];
  float* out = (float*)d_out;

  char* ws = (char*)d_ws;
  short* qb  = (short*)(ws);                // 4 MB  q  bf16 [BT][128]
  short* kb  = (short*)(ws + 4194304);      // 4 MB  k  bf16 [BT][128]
  short* vtb = (short*)(ws + 8388608);      // 4 MB  v^T bf16 [B][128][T]
  short* Wt  = (short*)(ws + 12582912);     // 0.75 MB  W^T bf16 [3][128][1024]

  wcvt_kernel<<<dim3(128, 3), 256, 0, stream>>>(Wq, Wk, Wv, Wt);
  proj_kernel<<<dim3(BT / 64, 3), 256, 0, stream>>>(x, Wt, qb, kb, vtb);
  attn_kernel<<<dim3(8 * 64), 256, 0, stream>>>(qb, kb, vtb, out);
}

// Round 5
// 184.255 us; speedup vs baseline: 1.7591x; 1.7591x over previous
//
#include <hip/hip_runtime.h>
#include <math.h>

#define B_ 8
#define T_ 2048
#define D_ 1024
#define H_ 128
#define BT (B_ * T_)

typedef short bf16x8 __attribute__((ext_vector_type(8)));
typedef float f32x4 __attribute__((ext_vector_type(4)));

static constexpr float SCALE = 0.08838834764831845f;  // 1/sqrt(128)

__device__ inline unsigned short f2b(float f) {
  unsigned int u = __float_as_uint(f);
  u += 0x7FFF + ((u >> 16) & 1);  // RNE
  return (unsigned short)(u >> 16);
}
__device__ inline unsigned int pk2(float a, float b) {
  return (unsigned int)f2b(a) | ((unsigned int)f2b(b) << 16);
}

// global (AS1) -> LDS (AS3) direct 16B copy; dest = wave-uniform base + lane*16
__device__ __forceinline__ void gll16(const void* g, void* l) {
  __builtin_amdgcn_global_load_lds(
      (const __attribute__((address_space(1))) void*)g,
      (__attribute__((address_space(3))) void*)l, 16, 0, 0);
}

// ---------------------------------------------------------------------------
// Setup: W[d][h] fp32 -> Wt[sel][h][d] bf16 (transposed). One-shot, tiny.
// ---------------------------------------------------------------------------
__global__ __launch_bounds__(256) void wcvt_kernel(
    const float* __restrict__ Wq, const float* __restrict__ Wk,
    const float* __restrict__ Wv, short* __restrict__ Wt) {
  const int sel = blockIdx.y;
  const float* W = sel == 0 ? Wq : (sel == 1 ? Wk : Wv);
  short* dst = Wt + (size_t)sel * D_ * H_;
  int slot = blockIdx.x * 256 + threadIdx.x;  // 32768 slots
  int d = slot >> 5, hg = slot & 31;
  float4 w = *(const float4*)(W + (size_t)d * H_ + hg * 4);
  dst[(size_t)(hg * 4 + 0) * D_ + d] = (short)f2b(w.x);
  dst[(size_t)(hg * 4 + 1) * D_ + d] = (short)f2b(w.y);
  dst[(size_t)(hg * 4 + 2) * D_ + d] = (short)f2b(w.z);
  dst[(size_t)(hg * 4 + 3) * D_ + d] = (short)f2b(w.w);
}

// ---------------------------------------------------------------------------
// Proj: C = X*W, bf16 MFMA. 128x128 tile per block (4 waves, wave tile 64x64),
// BK=64, 16 stages. LDS rows are UNPADDED 128B with XOR swizzle
// (16B-group g stored at g^(row&7)) => conflict-free frag reads AND
// global_load_lds-compatible staging for W. X is fp32: register-staged with
// short live ranges (load -> pack bf16 -> ds_write immediately; no cross-
// barrier liveness, so no spill — the round-3/4 failure mode).
// ---------------------------------------------------------------------------
__global__ __launch_bounds__(256) void proj_kernel(
    const float* __restrict__ x, const short* __restrict__ Wt,
    short* __restrict__ qb, short* __restrict__ kb, short* __restrict__ vtb) {
  __shared__ alignas(16) char smem[36864];  // 32 KB tiles / 34.8 KB epilogue
  short* Xs = (short*)smem;             // [128][64] bf16, swizzled
  short* Ws = (short*)(smem + 16384);   // [128][64] bf16, swizzled

  const int tid = threadIdx.x;
  const int wave = tid >> 6, lane = tid & 63;
  const int ln = lane & 15, quad = lane >> 4;
  const int mw = wave & 1, nw = wave >> 1;  // 2x2 wave grid of 64x64 subtiles
  const int sel = blockIdx.y;
  const int row0 = blockIdx.x * 128;
  const short* W = Wt + (size_t)sel * (size_t)(D_ * H_);

  f32x4 acc[4][4];
#pragma unroll
  for (int mi = 0; mi < 4; ++mi)
#pragma unroll
    for (int ni = 0; ni < 4; ++ni) acc[mi][ni] = (f32x4){0.f, 0.f, 0.f, 0.f};

  for (int s = 0; s < 16; ++s) {
    const int k0 = s * 64;
    if (s) __syncthreads();  // previous compute done; LDS reusable

    // W tile 128x64 via global_load_lds: 4 issues/wave, each 8 rows x 128 B.
    // LDS slot g' holds global group g'^(n&7)  (swizzle in source address).
#pragma unroll
    for (int j = 0; j < 4; ++j) {
      const int rbase = wave * 32 + j * 8;
      const int n = rbase + (lane >> 3);
      const int gp = (lane & 7) ^ (n & 7);
      gll16(W + (size_t)n * D_ + k0 + gp * 8, (char*)Ws + rbase * 128);
    }

    // X tile 128x64 fp32 -> bf16, swizzled store (short live ranges)
    {
      float4 xr[8];
#pragma unroll
      for (int i = 0; i < 8; ++i) {
        int fid = tid + i * 256;           // 2048 float4 slots
        int r = fid >> 4, g4 = fid & 15;   // row, 16B-fp32 group
        xr[i] = *(const float4*)(x + (size_t)(row0 + r) * D_ + k0 + g4 * 4);
      }
#pragma unroll
      for (int i = 0; i < 8; ++i) {
        int fid = tid + i * 256;
        int r = fid >> 4, g4 = fid & 15;
        int g = g4 >> 1, half = g4 & 1;    // bf16 16B-group, 8B half
        unsigned int* p = (unsigned int*)&Xs[r * 64 + ((g ^ (r & 7)) * 8) + half * 4];
        p[0] = pk2(xr[i].x, xr[i].y);
        p[1] = pk2(xr[i].z, xr[i].w);
      }
    }
    __syncthreads();  // drains vmcnt (gll) + lgkm (ds_write)

#pragma unroll
    for (int kk = 0; kk < 2; ++kk) {
      bf16x8 a[4];
#pragma unroll
      for (int mi = 0; mi < 4; ++mi) {
        int r = mw * 64 + mi * 16 + ln;
        int g = kk * 4 + quad;
        a[mi] = *(bf16x8*)&Xs[r * 64 + ((g ^ (r & 7)) * 8)];
      }
#pragma unroll
      for (int ni = 0; ni < 4; ++ni) {
        int n = nw * 64 + ni * 16 + ln;
        int g = kk * 4 + quad;
        bf16x8 bb = *(bf16x8*)&Ws[n * 64 + ((g ^ (n & 7)) * 8)];
#pragma unroll
        for (int mi = 0; mi < 4; ++mi)
          acc[mi][ni] = __builtin_amdgcn_mfma_f32_16x16x32_bf16(a[mi], bb, acc[mi][ni], 0, 0, 0);
      }
    }
  }

  __syncthreads();  // tiles dead; reuse smem for epilogue repack
  short* Cs = (short*)smem;  // [128][136] bf16 = 34816 B
  if (sel < 2) {
    short* out = sel ? kb : qb;
#pragma unroll
    for (int mi = 0; mi < 4; ++mi)
#pragma unroll
      for (int ni = 0; ni < 4; ++ni)
#pragma unroll
        for (int rr = 0; rr < 4; ++rr)
          Cs[(mw * 64 + mi * 16 + quad * 4 + rr) * 136 + nw * 64 + ni * 16 + ln] =
              (short)f2b(acc[mi][ni][rr]);
    __syncthreads();
#pragma unroll
    for (int i = 0; i < 8; ++i) {
      int slot = tid + i * 256;            // 2048 int4 slots: 128 rows x 16
      int r = slot >> 4, g = slot & 15;
      *(int4*)(out + (size_t)(row0 + r) * H_ + g * 8) = *(int4*)&Cs[r * 136 + g * 8];
    }
  } else {
    // transpose through LDS, write vt[b][h][t] coalesced
#pragma unroll
    for (int mi = 0; mi < 4; ++mi)
#pragma unroll
      for (int ni = 0; ni < 4; ++ni)
#pragma unroll
        for (int rr = 0; rr < 4; ++rr)
          Cs[(nw * 64 + ni * 16 + ln) * 136 + mw * 64 + mi * 16 + quad * 4 + rr] =
              (short)f2b(acc[mi][ni][rr]);
    __syncthreads();
    const int b = row0 >> 11, t0 = row0 & 2047;
#pragma unroll
    for (int i = 0; i < 8; ++i) {
      int slot = tid + i * 256;            // 2048 int4 slots: 128 h x 16
      int h = slot >> 4, g = slot & 15;
      *(int4*)(vtb + (size_t)(b * H_ + h) * T_ + t0 + g * 8) = *(int4*)&Cs[h * 136 + g * 8];
    }
  }
}

// ---------------------------------------------------------------------------
// Attention: round-2 version verbatim (known good: no spill, ~65 us).
// Flash-style MFMA, 32 queries/block, 64-key chunks.
// ---------------------------------------------------------------------------
__global__ __launch_bounds__(256) void attn_kernel(
    const short* __restrict__ qb, const short* __restrict__ kb,
    const short* __restrict__ vtb, float* __restrict__ out) {
  __shared__ alignas(16) short Ks[64 * 136];   // [64][136] (+8 pad)
  __shared__ alignas(16) short Vt[128 * 72];   // [128][72] (+8 pad)
  __shared__ alignas(16) float Sf[32 * 65];    // [32][65] f32
  __shared__ alignas(16) short P[32 * 72];     // [32][72] bf16
  __shared__ float aA[32], lL[32];

  const int tid = threadIdx.x;
  const int wave = tid >> 6, lane = tid & 63;
  const int ln = lane & 15, quad = lane >> 4;
  const int b = blockIdx.x >> 6;
  const int tile = 63 - (blockIdx.x & 63);  // heavy tiles first
  const int q0 = tile * 32;

  bf16x8 qfr[2][4];  // Q frags resident in registers
#pragma unroll
  for (int m = 0; m < 2; ++m)
#pragma unroll
    for (int kk = 0; kk < 4; ++kk)
      qfr[m][kk] = *(const bf16x8*)(qb + (size_t)(b * T_ + q0 + m * 16 + ln) * H_ +
                                    kk * 32 + quad * 8);

  f32x4 oacc[2][2];
#pragma unroll
  for (int m = 0; m < 2; ++m)
#pragma unroll
    for (int nt = 0; nt < 2; ++nt) oacc[m][nt] = (f32x4){0.f, 0.f, 0.f, 0.f};

  const int srow = tid >> 3, l8 = tid & 7;
  float m_run = -INFINITY, l_run = 0.f;

  const int nch = ((q0 + 31) >> 6) + 1;
  for (int ch = 0; ch < nch; ++ch) {
    const int s0 = ch * 64;
    if (ch) __syncthreads();  // prev PV done before overwriting Ks/Vt
#pragma unroll
    for (int w = 0; w < 4; ++w) {
      int i = tid + w * 256;
      int r = i >> 4, g = i & 15;
      *(int4*)&Ks[r * 136 + g * 8] =
          *(const int4*)(kb + (size_t)(b * T_ + s0 + r) * H_ + g * 8);
      int h = i >> 3, g2 = i & 7;
      *(int4*)&Vt[h * 72 + g2 * 8] =
          *(const int4*)(vtb + (size_t)(b * H_ + h) * T_ + s0 + g2 * 8);
    }
    __syncthreads();

    // S = Q K^T : each wave 32 queries x 16 keys
    f32x4 sacc[2];
    sacc[0] = (f32x4){0.f, 0.f, 0.f, 0.f};
    sacc[1] = (f32x4){0.f, 0.f, 0.f, 0.f};
#pragma unroll
    for (int kk = 0; kk < 4; ++kk) {
      bf16x8 bk = *(bf16x8*)&Ks[(wave * 16 + ln) * 136 + kk * 32 + quad * 8];
#pragma unroll
      for (int m = 0; m < 2; ++m)
        sacc[m] = __builtin_amdgcn_mfma_f32_16x16x32_bf16(qfr[m][kk], bk, sacc[m], 0, 0, 0);
    }
#pragma unroll
    for (int m = 0; m < 2; ++m)
#pragma unroll
      for (int r = 0; r < 4; ++r)
        Sf[(m * 16 + quad * 4 + r) * 65 + wave * 16 + ln] = sacc[m][r];
    __syncthreads();

    // online softmax: 8 lanes per row
    float sv[8];
    const int qg = q0 + srow;
#pragma unroll
    for (int i = 0; i < 8; ++i) {
      float s = Sf[srow * 65 + l8 * 8 + i] * SCALE;
      sv[i] = (s0 + l8 * 8 + i <= qg) ? s : -INFINITY;
    }
    float mx = sv[0];
#pragma unroll
    for (int i = 1; i < 8; ++i) mx = fmaxf(mx, sv[i]);
    mx = fmaxf(mx, __shfl_xor(mx, 1));
    mx = fmaxf(mx, __shfl_xor(mx, 2));
    mx = fmaxf(mx, __shfl_xor(mx, 4));
    const float mnew = fmaxf(m_run, mx);
    const float alpha = __expf(m_run - mnew);
    float p[8], ps = 0.f;
#pragma unroll
    for (int i = 0; i < 8; ++i) {
      p[i] = __expf(sv[i] - mnew);
      ps += p[i];
    }
    ps += __shfl_xor(ps, 1);
    ps += __shfl_xor(ps, 2);
    ps += __shfl_xor(ps, 4);
    l_run = l_run * alpha + ps;
    m_run = mnew;
    int4 pw;
    pw.x = (int)pk2(p[0], p[1]);
    pw.y = (int)pk2(p[2], p[3]);
    pw.z = (int)pk2(p[4], p[5]);
    pw.w = (int)pk2(p[6], p[7]);
    *(int4*)&P[srow * 72 + l8 * 8] = pw;
    if (l8 == 0) aA[srow] = alpha;
    __syncthreads();

    // O = O*alpha + P V : each wave 32 queries x 32 head-dims
    const int h0 = wave * 32;
    float ar[2][4];
#pragma unroll
    for (int m = 0; m < 2; ++m)
#pragma unroll
      for (int r = 0; r < 4; ++r) ar[m][r] = aA[m * 16 + quad * 4 + r];
#pragma unroll
    for (int m = 0; m < 2; ++m)
#pragma unroll
      for (int nt = 0; nt < 2; ++nt)
#pragma unroll
        for (int r = 0; r < 4; ++r) oacc[m][nt][r] *= ar[m][r];
#pragma unroll
    for (int ks = 0; ks < 2; ++ks) {
      bf16x8 pa[2];
      pa[0] = *(bf16x8*)&P[ln * 72 + ks * 32 + quad * 8];
      pa[1] = *(bf16x8*)&P[(16 + ln) * 72 + ks * 32 + quad * 8];
#pragma unroll
      for (int nt = 0; nt < 2; ++nt) {
        bf16x8 bv = *(bf16x8*)&Vt[(h0 + nt * 16 + ln) * 72 + ks * 32 + quad * 8];
#pragma unroll
        for (int m = 0; m < 2; ++m)
          oacc[m][nt] = __builtin_amdgcn_mfma_f32_16x16x32_bf16(pa[m], bv, oacc[m][nt], 0, 0, 0);
      }
    }
  }

  if (l8 == 0) lL[srow] = l_run;
  __syncthreads();
  const int h0 = wave * 32;
#pragma unroll
  for (int m = 0; m < 2; ++m) {
    float linv[4];
#pragma unroll
    for (int r = 0; r < 4; ++r) linv[r] = 1.f / lL[m * 16 + quad * 4 + r];
#pragma unroll
    for (int nt = 0; nt < 2; ++nt)
#pragma unroll
      for (int r = 0; r < 4; ++r) {
        int row = q0 + m * 16 + quad * 4 + r;
        out[(size_t)(b * T_ + row) * H_ + h0 + nt * 16 + ln] = oacc[m][nt][r] * linv[r];
      }
  }
}

// ---------------------------------------------------------------------------
extern "C" void kernel_launch(void* const* d_in, const int* in_sizes, int n_in,
                              void* d_out, int out_size, void* d_ws, size_t ws_size,
                              hipStream_t stream) {
  const float* x  = (const float*)d_in[0];
  const float* Wq = (const float*)d_in[1];
  const float* Wk = (const float*)d_in[2];
  const float* Wv = (const float*)d_in[3];
  float* out = (float*)d_out;

  char* ws = (char*)d_ws;
  short* qb  = (short*)(ws);                // 4 MB  q  bf16 [BT][128]
  short* kb  = (short*)(ws + 4194304);      // 4 MB  k  bf16 [BT][128]
  short* vtb = (short*)(ws + 8388608);      // 4 MB  v^T bf16 [B][128][T]
  short* Wt  = (short*)(ws + 12582912);     // 0.75 MB  W^T bf16 [3][128][1024]

  wcvt_kernel<<<dim3(128, 3), 256, 0, stream>>>(Wq, Wk, Wv, Wt);
  proj_kernel<<<dim3(BT / 128, 3), 256, 0, stream>>>(x, Wt, qb, kb, vtb);
  attn_kernel<<<dim3(8 * 64), 256, 0, stream>>>(qb, kb, vtb, out);
}

// Round 6
// 182.644 us; speedup vs baseline: 1.7746x; 1.0088x over previous
//
#include <hip/hip_runtime.h>
#include <math.h>

#define B_ 8
#define T_ 2048
#define D_ 1024
#define H_ 128
#define BT (B_ * T_)

typedef short bf16x8 __attribute__((ext_vector_type(8)));
typedef float f32x4 __attribute__((ext_vector_type(4)));

static constexpr float SCALE = 0.08838834764831845f;  // 1/sqrt(128)

__device__ inline unsigned short f2b(float f) {
  unsigned int u = __float_as_uint(f);
  u += 0x7FFF + ((u >> 16) & 1);  // RNE
  return (unsigned short)(u >> 16);
}
__device__ inline unsigned int pk2(float a, float b) {
  return (unsigned int)f2b(a) | ((unsigned int)f2b(b) << 16);
}

// global (AS1) -> LDS (AS3) direct 16B copy; dest = wave-uniform base + lane*16
__device__ __forceinline__ void gll16(const void* g, void* l) {
  __builtin_amdgcn_global_load_lds(
      (const __attribute__((address_space(1))) void*)g,
      (__attribute__((address_space(3))) void*)l, 16, 0, 0);
}

// ---------------------------------------------------------------------------
// Setup: W[d][h] fp32 -> Wt[sel][h][d] bf16, transposed THROUGH LDS so global
// stores are coalesced 16B runs (round-5 version did 2KB-stride short stores).
// grid (D/64, 3) x 256 thr. Block handles 64d x 128h.
// ---------------------------------------------------------------------------
__global__ __launch_bounds__(256) void wcvt_kernel(
    const float* __restrict__ Wq, const float* __restrict__ Wk,
    const float* __restrict__ Wv, short* __restrict__ Wt) {
  __shared__ short Wls[128 * 72];  // [h][d] bf16, pitch 72
  const int sel = blockIdx.y;
  const float* W = sel == 0 ? Wq : (sel == 1 ? Wk : Wv);
  const int d0 = blockIdx.x * 64;
  const int tid = threadIdx.x;
#pragma unroll
  for (int i = 0; i < 8; ++i) {
    int slot = tid + i * 256;         // 2048 float4 slots: 64 d x 32 h-groups
    int r = slot >> 5, hg = slot & 31;
    float4 w = *(const float4*)(W + (size_t)(d0 + r) * H_ + hg * 4);
    Wls[(hg * 4 + 0) * 72 + r] = (short)f2b(w.x);
    Wls[(hg * 4 + 1) * 72 + r] = (short)f2b(w.y);
    Wls[(hg * 4 + 2) * 72 + r] = (short)f2b(w.z);
    Wls[(hg * 4 + 3) * 72 + r] = (short)f2b(w.w);
  }
  __syncthreads();
  short* dst = Wt + (size_t)sel * D_ * H_;
#pragma unroll
  for (int i = 0; i < 4; ++i) {
    int slot = tid + i * 256;         // 1024 int4 slots: 128 h x 8 d-groups
    int h = slot >> 3, g = slot & 7;
    *(int4*)(dst + (size_t)h * D_ + d0 + g * 8) = *(int4*)&Wls[h * 72 + g * 8];
  }
}

// ---------------------------------------------------------------------------
// Proj: unchanged from round 5 (128x128 tile, gll W staging, swizzled LDS).
// ---------------------------------------------------------------------------
__global__ __launch_bounds__(256) void proj_kernel(
    const float* __restrict__ x, const short* __restrict__ Wt,
    short* __restrict__ qb, short* __restrict__ kb, short* __restrict__ vtb) {
  __shared__ alignas(16) char smem[36864];
  short* Xs = (short*)smem;             // [128][64] bf16, swizzled
  short* Ws = (short*)(smem + 16384);   // [128][64] bf16, swizzled

  const int tid = threadIdx.x;
  const int wave = tid >> 6, lane = tid & 63;
  const int ln = lane & 15, quad = lane >> 4;
  const int mw = wave & 1, nw = wave >> 1;
  const int sel = blockIdx.y;
  const int row0 = blockIdx.x * 128;
  const short* W = Wt + (size_t)sel * (size_t)(D_ * H_);

  f32x4 acc[4][4];
#pragma unroll
  for (int mi = 0; mi < 4; ++mi)
#pragma unroll
    for (int ni = 0; ni < 4; ++ni) acc[mi][ni] = (f32x4){0.f, 0.f, 0.f, 0.f};

  for (int s = 0; s < 16; ++s) {
    const int k0 = s * 64;
    if (s) __syncthreads();

#pragma unroll
    for (int j = 0; j < 4; ++j) {
      const int rbase = wave * 32 + j * 8;
      const int n = rbase + (lane >> 3);
      const int gp = (lane & 7) ^ (n & 7);
      gll16(W + (size_t)n * D_ + k0 + gp * 8, (char*)Ws + rbase * 128);
    }
    {
      float4 xr[8];
#pragma unroll
      for (int i = 0; i < 8; ++i) {
        int fid = tid + i * 256;
        int r = fid >> 4, g4 = fid & 15;
        xr[i] = *(const float4*)(x + (size_t)(row0 + r) * D_ + k0 + g4 * 4);
      }
#pragma unroll
      for (int i = 0; i < 8; ++i) {
        int fid = tid + i * 256;
        int r = fid >> 4, g4 = fid & 15;
        int g = g4 >> 1, half = g4 & 1;
        unsigned int* p = (unsigned int*)&Xs[r * 64 + ((g ^ (r & 7)) * 8) + half * 4];
        p[0] = pk2(xr[i].x, xr[i].y);
        p[1] = pk2(xr[i].z, xr[i].w);
      }
    }
    __syncthreads();

#pragma unroll
    for (int kk = 0; kk < 2; ++kk) {
      bf16x8 a[4];
#pragma unroll
      for (int mi = 0; mi < 4; ++mi) {
        int r = mw * 64 + mi * 16 + ln;
        int g = kk * 4 + quad;
        a[mi] = *(bf16x8*)&Xs[r * 64 + ((g ^ (r & 7)) * 8)];
      }
#pragma unroll
      for (int ni = 0; ni < 4; ++ni) {
        int n = nw * 64 + ni * 16 + ln;
        int g = kk * 4 + quad;
        bf16x8 bb = *(bf16x8*)&Ws[n * 64 + ((g ^ (n & 7)) * 8)];
#pragma unroll
        for (int mi = 0; mi < 4; ++mi)
          acc[mi][ni] = __builtin_amdgcn_mfma_f32_16x16x32_bf16(a[mi], bb, acc[mi][ni], 0, 0, 0);
      }
    }
  }

  __syncthreads();
  short* Cs = (short*)smem;  // [128][136] bf16
  if (sel < 2) {
    short* out = sel ? kb : qb;
#pragma unroll
    for (int mi = 0; mi < 4; ++mi)
#pragma unroll
      for (int ni = 0; ni < 4; ++ni)
#pragma unroll
        for (int rr = 0; rr < 4; ++rr)
          Cs[(mw * 64 + mi * 16 + quad * 4 + rr) * 136 + nw * 64 + ni * 16 + ln] =
              (short)f2b(acc[mi][ni][rr]);
    __syncthreads();
#pragma unroll
    for (int i = 0; i < 8; ++i) {
      int slot = tid + i * 256;
      int r = slot >> 4, g = slot & 15;
      *(int4*)(out + (size_t)(row0 + r) * H_ + g * 8) = *(int4*)&Cs[r * 136 + g * 8];
    }
  } else {
#pragma unroll
    for (int mi = 0; mi < 4; ++mi)
#pragma unroll
      for (int ni = 0; ni < 4; ++ni)
#pragma unroll
        for (int rr = 0; rr < 4; ++rr)
          Cs[(nw * 64 + ni * 16 + ln) * 136 + mw * 64 + mi * 16 + quad * 4 + rr] =
              (short)f2b(acc[mi][ni][rr]);
    __syncthreads();
    const int b = row0 >> 11, t0 = row0 & 2047;
#pragma unroll
    for (int i = 0; i < 8; ++i) {
      int slot = tid + i * 256;
      int h = slot >> 4, g = slot & 15;
      *(int4*)(vtb + (size_t)(b * H_ + h) * T_ + t0 + g * 8) = *(int4*)&Cs[h * 136 + g * 8];
    }
  }
}

// ---------------------------------------------------------------------------
// Attention: flash-style MFMA, 32 queries/block, 64-key chunks.
// K/V staged via DOUBLE-BUFFERED global_load_lds (zero data registers -> no
// spill; issue-early/drain-late hides the load latency behind compute).
// K/V LDS unpadded + XOR swizzle on 16B groups (2-way conflicts = free).
// ---------------------------------------------------------------------------
__global__ __launch_bounds__(256) void attn_kernel(
    const short* __restrict__ qb, const short* __restrict__ kb,
    const short* __restrict__ vtb, float* __restrict__ out) {
  __shared__ alignas(16) short Ks[2][64 * 128];   // 2 x 16 KB, swizzled
  __shared__ alignas(16) short Vt[2][128 * 64];   // 2 x 16 KB, swizzled
  __shared__ alignas(16) float Sf[32 * 65];       // [32][65] f32 (padded)
  __shared__ alignas(16) short P[32 * 72];        // [32][72] bf16 (padded)
  __shared__ float aA[32], lL[32];

  const int tid = threadIdx.x;
  const int wave = tid >> 6, lane = tid & 63;
  const int ln = lane & 15, quad = lane >> 4;
  const int b = blockIdx.x >> 6;
  const int tile = 63 - (blockIdx.x & 63);  // heavy tiles first
  const int q0 = tile * 32;

  bf16x8 qfr[2][4];  // Q frags resident in registers
#pragma unroll
  for (int m = 0; m < 2; ++m)
#pragma unroll
    for (int kk = 0; kk < 4; ++kk)
      qfr[m][kk] = *(const bf16x8*)(qb + (size_t)(b * T_ + q0 + m * 16 + ln) * H_ +
                                    kk * 32 + quad * 8);

  f32x4 oacc[2][2];
#pragma unroll
  for (int m = 0; m < 2; ++m)
#pragma unroll
    for (int nt = 0; nt < 2; ++nt) oacc[m][nt] = (f32x4){0.f, 0.f, 0.f, 0.f};

  const int srow = tid >> 3, l8 = tid & 7;
  float m_run = -INFINITY, l_run = 0.f;

  // async stage of one 64-key chunk into buffer `bf` (8 gll issues per wave)
  auto stage = [&](int bf, int s0) {
    // K: 64 rows x 256B; per wave 16 rows, 4 issues of 4 rows
#pragma unroll
    for (int j = 0; j < 4; ++j) {
      const int rb = wave * 16 + j * 4;
      const int r = rb + (lane >> 4);
      const int gp = (lane & 15) ^ (r & 7);
      gll16(kb + (size_t)(b * T_ + s0 + r) * H_ + gp * 8,
            (char*)&Ks[bf][0] + rb * 256);
    }
    // V^T: 128 rows x 128B; per wave 32 rows, 4 issues of 8 rows
#pragma unroll
    for (int j = 0; j < 4; ++j) {
      const int hb = wave * 32 + j * 8;
      const int h = hb + (lane >> 3);
      const int gp = (lane & 7) ^ (h & 7);
      gll16(vtb + (size_t)(b * H_ + h) * T_ + s0 + gp * 8,
            (char*)&Vt[bf][0] + hb * 128);
    }
  };

  const int nch = ((q0 + 31) >> 6) + 1;
  stage(0, 0);  // prologue: chunk 0 -> buf 0

  for (int ch = 0; ch < nch; ++ch) {
    const int cur = ch & 1;
    const int s0 = ch * 64;
    // drains gll for buf[cur]; protects buf[cur^1] from overwrite (prev PV done)
    __syncthreads();
    if (ch + 1 < nch) stage(cur ^ 1, s0 + 64);  // async fill; flies during compute

    // S = Q K^T : each wave 32 queries x 16 keys (keys wave*16..+15)
    f32x4 sacc[2];
    sacc[0] = (f32x4){0.f, 0.f, 0.f, 0.f};
    sacc[1] = (f32x4){0.f, 0.f, 0.f, 0.f};
#pragma unroll
    for (int kk = 0; kk < 4; ++kk) {
      const int r = wave * 16 + ln;
      bf16x8 bk = *(bf16x8*)&Ks[cur][r * 128 + (((kk * 4 + quad) ^ (r & 7)) * 8)];
#pragma unroll
      for (int m = 0; m < 2; ++m)
        sacc[m] = __builtin_amdgcn_mfma_f32_16x16x32_bf16(qfr[m][kk], bk, sacc[m], 0, 0, 0);
    }
#pragma unroll
    for (int m = 0; m < 2; ++m)
#pragma unroll
      for (int r = 0; r < 4; ++r)
        Sf[(m * 16 + quad * 4 + r) * 65 + wave * 16 + ln] = sacc[m][r];
    __syncthreads();

    // online softmax: 8 lanes per row
    float sv[8];
    const int qg = q0 + srow;
#pragma unroll
    for (int i = 0; i < 8; ++i) {
      float s = Sf[srow * 65 + l8 * 8 + i] * SCALE;
      sv[i] = (s0 + l8 * 8 + i <= qg) ? s : -INFINITY;
    }
    float mx = sv[0];
#pragma unroll
    for (int i = 1; i < 8; ++i) mx = fmaxf(mx, sv[i]);
    mx = fmaxf(mx, __shfl_xor(mx, 1));
    mx = fmaxf(mx, __shfl_xor(mx, 2));
    mx = fmaxf(mx, __shfl_xor(mx, 4));
    const float mnew = fmaxf(m_run, mx);
    const float alpha = __expf(m_run - mnew);
    float p[8], ps = 0.f;
#pragma unroll
    for (int i = 0; i < 8; ++i) {
      p[i] = __expf(sv[i] - mnew);
      ps += p[i];
    }
    ps += __shfl_xor(ps, 1);
    ps += __shfl_xor(ps, 2);
    ps += __shfl_xor(ps, 4);
    l_run = l_run * alpha + ps;
    m_run = mnew;
    int4 pw;
    pw.x = (int)pk2(p[0], p[1]);
    pw.y = (int)pk2(p[2], p[3]);
    pw.z = (int)pk2(p[4], p[5]);
    pw.w = (int)pk2(p[6], p[7]);
    *(int4*)&P[srow * 72 + l8 * 8] = pw;
    if (l8 == 0) aA[srow] = alpha;
    __syncthreads();

    // O = O*alpha + P V : each wave 32 queries x 32 head-dims
    const int h0 = wave * 32;
    float ar[2][4];
#pragma unroll
    for (int m = 0; m < 2; ++m)
#pragma unroll
      for (int r = 0; r < 4; ++r) ar[m][r] = aA[m * 16 + quad * 4 + r];
#pragma unroll
    for (int m = 0; m < 2; ++m)
#pragma unroll
      for (int nt = 0; nt < 2; ++nt)
#pragma unroll
        for (int r = 0; r < 4; ++r) oacc[m][nt][r] *= ar[m][r];
#pragma unroll
    for (int ks = 0; ks < 2; ++ks) {
      bf16x8 pa[2];
      pa[0] = *(bf16x8*)&P[ln * 72 + ks * 32 + quad * 8];
      pa[1] = *(bf16x8*)&P[(16 + ln) * 72 + ks * 32 + quad * 8];
#pragma unroll
      for (int nt = 0; nt < 2; ++nt) {
        const int n = h0 + nt * 16 + ln;
        bf16x8 bv = *(bf16x8*)&Vt[cur][n * 64 + (((ks * 4 + quad) ^ (n & 7)) * 8)];
#pragma unroll
        for (int m = 0; m < 2; ++m)
          oacc[m][nt] = __builtin_amdgcn_mfma_f32_16x16x32_bf16(pa[m], bv, oacc[m][nt], 0, 0, 0);
      }
    }
  }

  if (l8 == 0) lL[srow] = l_run;
  __syncthreads();
  const int h0 = wave * 32;
#pragma unroll
  for (int m = 0; m < 2; ++m) {
    float linv[4];
#pragma unroll
    for (int r = 0; r < 4; ++r) linv[r] = 1.f / lL[m * 16 + quad * 4 + r];
#pragma unroll
    for (int nt = 0; nt < 2; ++nt)
#pragma unroll
      for (int r = 0; r < 4; ++r) {
        int row = q0 + m * 16 + quad * 4 + r;
        out[(size_t)(b * T_ + row) * H_ + h0 + nt * 16 + ln] = oacc[m][nt][r] * linv[r];
      }
  }
}

// ---------------------------------------------------------------------------
extern "C" void kernel_launch(void* const* d_in, const int* in_sizes, int n_in,
                              void* d_out, int out_size, void* d_ws, size_t ws_size,
                              hipStream_t stream) {
  const float* x  = (const float*)d_in[0];
  const float* Wq = (const float*)d_in[1];
  const float* Wk = (const float*)d_in[2];
  const float* Wv = (const float*)d_in[3];
  float* out = (float*)d_out;

  char* ws = (char*)d_ws;
  short* qb  = (short*)(ws);                // 4 MB  q  bf16 [BT][128]
  short* kb  = (short*)(ws + 4194304);      // 4 MB  k  bf16 [BT][128]
  short* vtb = (short*)(ws + 8388608);      // 4 MB  v^T bf16 [B][128][T]
  short* Wt  = (short*)(ws + 12582912);     // 0.75 MB  W^T bf16 [3][128][1024]

  wcvt_kernel<<<dim3(D_ / 64, 3), 256, 0, stream>>>(Wq, Wk, Wv, Wt);
  proj_kernel<<<dim3(BT / 128, 3), 256, 0, stream>>>(x, Wt, qb, kb, vtb);
  attn_kernel<<<dim3(8 * 64), 256, 0, stream>>>(qb, kb, vtb, out);
}

// Round 7
// 180.092 us; speedup vs baseline: 1.7998x; 1.0142x over previous
//
#include <hip/hip_runtime.h>
#include <math.h>

#define B_ 8
#define T_ 2048
#define D_ 1024
#define H_ 128
#define BT (B_ * T_)

typedef short bf16x8 __attribute__((ext_vector_type(8)));
typedef float f32x4 __attribute__((ext_vector_type(4)));

static constexpr float SCALE = 0.08838834764831845f;  // 1/sqrt(128)

__device__ inline unsigned short f2b(float f) {
  unsigned int u = __float_as_uint(f);
  u += 0x7FFF + ((u >> 16) & 1);  // RNE
  return (unsigned short)(u >> 16);
}
__device__ inline unsigned int pk2(float a, float b) {
  return (unsigned int)f2b(a) | ((unsigned int)f2b(b) << 16);
}

// global (AS1) -> LDS (AS3) direct 16B copy; dest = wave-uniform base + lane*16
__device__ __forceinline__ void gll16(const void* g, void* l) {
  __builtin_amdgcn_global_load_lds(
      (const __attribute__((address_space(1))) void*)g,
      (__attribute__((address_space(3))) void*)l, 16, 0, 0);
}

// ---------------------------------------------------------------------------
// Setup: W[d][h] fp32 -> Wt[sel][h][d] bf16 through LDS, coalesced stores.
// ---------------------------------------------------------------------------
__global__ __launch_bounds__(256) void wcvt_kernel(
    const float* __restrict__ Wq, const float* __restrict__ Wk,
    const float* __restrict__ Wv, short* __restrict__ Wt) {
  __shared__ short Wls[128 * 72];  // [h][d] bf16, pitch 72
  const int sel = blockIdx.y;
  const float* W = sel == 0 ? Wq : (sel == 1 ? Wk : Wv);
  const int d0 = blockIdx.x * 64;
  const int tid = threadIdx.x;
#pragma unroll
  for (int i = 0; i < 8; ++i) {
    int slot = tid + i * 256;         // 2048 float4 slots: 64 d x 32 h-groups
    int r = slot >> 5, hg = slot & 31;
    float4 w = *(const float4*)(W + (size_t)(d0 + r) * H_ + hg * 4);
    Wls[(hg * 4 + 0) * 72 + r] = (short)f2b(w.x);
    Wls[(hg * 4 + 1) * 72 + r] = (short)f2b(w.y);
    Wls[(hg * 4 + 2) * 72 + r] = (short)f2b(w.z);
    Wls[(hg * 4 + 3) * 72 + r] = (short)f2b(w.w);
  }
  __syncthreads();
  short* dst = Wt + (size_t)sel * D_ * H_;
#pragma unroll
  for (int i = 0; i < 4; ++i) {
    int slot = tid + i * 256;         // 1024 int4 slots: 128 h x 8 d-groups
    int h = slot >> 3, g = slot & 7;
    *(int4*)(dst + (size_t)h * D_ + d0 + g * 8) = *(int4*)&Wls[h * 72 + g * 8];
  }
}

// ---------------------------------------------------------------------------
// Proj: unchanged (128x128 tile, gll W staging, swizzled LDS).
// ---------------------------------------------------------------------------
__global__ __launch_bounds__(256) void proj_kernel(
    const float* __restrict__ x, const short* __restrict__ Wt,
    short* __restrict__ qb, short* __restrict__ kb, short* __restrict__ vtb) {
  __shared__ alignas(16) char smem[36864];
  short* Xs = (short*)smem;             // [128][64] bf16, swizzled
  short* Ws = (short*)(smem + 16384);   // [128][64] bf16, swizzled

  const int tid = threadIdx.x;
  const int wave = tid >> 6, lane = tid & 63;
  const int ln = lane & 15, quad = lane >> 4;
  const int mw = wave & 1, nw = wave >> 1;
  const int sel = blockIdx.y;
  const int row0 = blockIdx.x * 128;
  const short* W = Wt + (size_t)sel * (size_t)(D_ * H_);

  f32x4 acc[4][4];
#pragma unroll
  for (int mi = 0; mi < 4; ++mi)
#pragma unroll
    for (int ni = 0; ni < 4; ++ni) acc[mi][ni] = (f32x4){0.f, 0.f, 0.f, 0.f};

  for (int s = 0; s < 16; ++s) {
    const int k0 = s * 64;
    if (s) __syncthreads();

#pragma unroll
    for (int j = 0; j < 4; ++j) {
      const int rbase = wave * 32 + j * 8;
      const int n = rbase + (lane >> 3);
      const int gp = (lane & 7) ^ (n & 7);
      gll16(W + (size_t)n * D_ + k0 + gp * 8, (char*)Ws + rbase * 128);
    }
    {
      float4 xr[8];
#pragma unroll
      for (int i = 0; i < 8; ++i) {
        int fid = tid + i * 256;
        int r = fid >> 4, g4 = fid & 15;
        xr[i] = *(const float4*)(x + (size_t)(row0 + r) * D_ + k0 + g4 * 4);
      }
#pragma unroll
      for (int i = 0; i < 8; ++i) {
        int fid = tid + i * 256;
        int r = fid >> 4, g4 = fid & 15;
        int g = g4 >> 1, half = g4 & 1;
        unsigned int* p = (unsigned int*)&Xs[r * 64 + ((g ^ (r & 7)) * 8) + half * 4];
        p[0] = pk2(xr[i].x, xr[i].y);
        p[1] = pk2(xr[i].z, xr[i].w);
      }
    }
    __syncthreads();

#pragma unroll
    for (int kk = 0; kk < 2; ++kk) {
      bf16x8 a[4];
#pragma unroll
      for (int mi = 0; mi < 4; ++mi) {
        int r = mw * 64 + mi * 16 + ln;
        int g = kk * 4 + quad;
        a[mi] = *(bf16x8*)&Xs[r * 64 + ((g ^ (r & 7)) * 8)];
      }
#pragma unroll
      for (int ni = 0; ni < 4; ++ni) {
        int n = nw * 64 + ni * 16 + ln;
        int g = kk * 4 + quad;
        bf16x8 bb = *(bf16x8*)&Ws[n * 64 + ((g ^ (n & 7)) * 8)];
#pragma unroll
        for (int mi = 0; mi < 4; ++mi)
          acc[mi][ni] = __builtin_amdgcn_mfma_f32_16x16x32_bf16(a[mi], bb, acc[mi][ni], 0, 0, 0);
      }
    }
  }

  __syncthreads();
  short* Cs = (short*)smem;  // [128][136] bf16
  if (sel < 2) {
    short* out = sel ? kb : qb;
#pragma unroll
    for (int mi = 0; mi < 4; ++mi)
#pragma unroll
      for (int ni = 0; ni < 4; ++ni)
#pragma unroll
        for (int rr = 0; rr < 4; ++rr)
          Cs[(mw * 64 + mi * 16 + quad * 4 + rr) * 136 + nw * 64 + ni * 16 + ln] =
              (short)f2b(acc[mi][ni][rr]);
    __syncthreads();
#pragma unroll
    for (int i = 0; i < 8; ++i) {
      int slot = tid + i * 256;
      int r = slot >> 4, g = slot & 15;
      *(int4*)(out + (size_t)(row0 + r) * H_ + g * 8) = *(int4*)&Cs[r * 136 + g * 8];
    }
  } else {
#pragma unroll
    for (int mi = 0; mi < 4; ++mi)
#pragma unroll
      for (int ni = 0; ni < 4; ++ni)
#pragma unroll
        for (int rr = 0; rr < 4; ++rr)
          Cs[(nw * 64 + ni * 16 + ln) * 136 + mw * 64 + mi * 16 + quad * 4 + rr] =
              (short)f2b(acc[mi][ni][rr]);
    __syncthreads();
    const int b = row0 >> 11, t0 = row0 & 2047;
#pragma unroll
    for (int i = 0; i < 8; ++i) {
      int slot = tid + i * 256;
      int h = slot >> 4, g = slot & 15;
      *(int4*)(vtb + (size_t)(b * H_ + h) * T_ + t0 + g * 8) = *(int4*)&Cs[h * 136 + g * 8];
    }
  }
}

// ---------------------------------------------------------------------------
// Attention: as round 6, but COMPLEMENTARY TILE PAIRING. Whole 512-block grid
// is co-resident (77 KB LDS -> 2 blocks/CU); old mapping put identical-size
// tiles on slots s and s+256 (same CU) -> worst-case 66-chunk CUs. New map:
// slot s (pass 0) gets tile j, slot s+256 (pass 1) gets tile 63-j, so every
// CU pair sums to 33-34 chunks.
// ---------------------------------------------------------------------------
__global__ __launch_bounds__(256) void attn_kernel(
    const short* __restrict__ qb, const short* __restrict__ kb,
    const short* __restrict__ vtb, float* __restrict__ out) {
  __shared__ alignas(16) short Ks[2][64 * 128];   // 2 x 16 KB, swizzled
  __shared__ alignas(16) short Vt[2][128 * 64];   // 2 x 16 KB, swizzled
  __shared__ alignas(16) float Sf[32 * 65];       // [32][65] f32 (padded)
  __shared__ alignas(16) short P[32 * 72];        // [32][72] bf16 (padded)
  __shared__ float aA[32], lL[32];

  const int tid = threadIdx.x;
  const int wave = tid >> 6, lane = tid & 63;
  const int ln = lane & 15, quad = lane >> 4;
  const int slot = blockIdx.x & 255;
  const int pass = blockIdx.x >> 8;           // 0 or 1
  const int b = slot >> 5;                    // 8 batches
  const int j = slot & 31;                    // 32 pair slots
  const int tile = pass ? (63 - j) : j;       // complementary pairing
  const int q0 = tile * 32;

  bf16x8 qfr[2][4];  // Q frags resident in registers
#pragma unroll
  for (int m = 0; m < 2; ++m)
#pragma unroll
    for (int kk = 0; kk < 4; ++kk)
      qfr[m][kk] = *(const bf16x8*)(qb + (size_t)(b * T_ + q0 + m * 16 + ln) * H_ +
                                    kk * 32 + quad * 8);

  f32x4 oacc[2][2];
#pragma unroll
  for (int m = 0; m < 2; ++m)
#pragma unroll
    for (int nt = 0; nt < 2; ++nt) oacc[m][nt] = (f32x4){0.f, 0.f, 0.f, 0.f};

  const int srow = tid >> 3, l8 = tid & 7;
  float m_run = -INFINITY, l_run = 0.f;

  // async stage of one 64-key chunk into buffer `bf` (8 gll issues per wave)
  auto stage = [&](int bf, int s0) {
#pragma unroll
    for (int jj = 0; jj < 4; ++jj) {
      const int rb = wave * 16 + jj * 4;
      const int r = rb + (lane >> 4);
      const int gp = (lane & 15) ^ (r & 7);
      gll16(kb + (size_t)(b * T_ + s0 + r) * H_ + gp * 8,
            (char*)&Ks[bf][0] + rb * 256);
    }
#pragma unroll
    for (int jj = 0; jj < 4; ++jj) {
      const int hb = wave * 32 + jj * 8;
      const int h = hb + (lane >> 3);
      const int gp = (lane & 7) ^ (h & 7);
      gll16(vtb + (size_t)(b * H_ + h) * T_ + s0 + gp * 8,
            (char*)&Vt[bf][0] + hb * 128);
    }
  };

  const int nch = ((q0 + 31) >> 6) + 1;
  stage(0, 0);  // prologue: chunk 0 -> buf 0

  for (int ch = 0; ch < nch; ++ch) {
    const int cur = ch & 1;
    const int s0 = ch * 64;
    __syncthreads();  // drains gll for buf[cur]; protects buf[cur^1]
    if (ch + 1 < nch) stage(cur ^ 1, s0 + 64);

    // S = Q K^T : each wave 32 queries x 16 keys
    f32x4 sacc[2];
    sacc[0] = (f32x4){0.f, 0.f, 0.f, 0.f};
    sacc[1] = (f32x4){0.f, 0.f, 0.f, 0.f};
#pragma unroll
    for (int kk = 0; kk < 4; ++kk) {
      const int r = wave * 16 + ln;
      bf16x8 bk = *(bf16x8*)&Ks[cur][r * 128 + (((kk * 4 + quad) ^ (r & 7)) * 8)];
#pragma unroll
      for (int m = 0; m < 2; ++m)
        sacc[m] = __builtin_amdgcn_mfma_f32_16x16x32_bf16(qfr[m][kk], bk, sacc[m], 0, 0, 0);
    }
#pragma unroll
    for (int m = 0; m < 2; ++m)
#pragma unroll
      for (int r = 0; r < 4; ++r)
        Sf[(m * 16 + quad * 4 + r) * 65 + wave * 16 + ln] = sacc[m][r];
    __syncthreads();

    // online softmax: 8 lanes per row
    float sv[8];
    const int qg = q0 + srow;
#pragma unroll
    for (int i = 0; i < 8; ++i) {
      float s = Sf[srow * 65 + l8 * 8 + i] * SCALE;
      sv[i] = (s0 + l8 * 8 + i <= qg) ? s : -INFINITY;
    }
    float mx = sv[0];
#pragma unroll
    for (int i = 1; i < 8; ++i) mx = fmaxf(mx, sv[i]);
    mx = fmaxf(mx, __shfl_xor(mx, 1));
    mx = fmaxf(mx, __shfl_xor(mx, 2));
    mx = fmaxf(mx, __shfl_xor(mx, 4));
    const float mnew = fmaxf(m_run, mx);
    const float alpha = __expf(m_run - mnew);
    float p[8], ps = 0.f;
#pragma unroll
    for (int i = 0; i < 8; ++i) {
      p[i] = __expf(sv[i] - mnew);
      ps += p[i];
    }
    ps += __shfl_xor(ps, 1);
    ps += __shfl_xor(ps, 2);
    ps += __shfl_xor(ps, 4);
    l_run = l_run * alpha + ps;
    m_run = mnew;
    int4 pw;
    pw.x = (int)pk2(p[0], p[1]);
    pw.y = (int)pk2(p[2], p[3]);
    pw.z = (int)pk2(p[4], p[5]);
    pw.w = (int)pk2(p[6], p[7]);
    *(int4*)&P[srow * 72 + l8 * 8] = pw;
    if (l8 == 0) aA[srow] = alpha;
    __syncthreads();

    // O = O*alpha + P V : each wave 32 queries x 32 head-dims
    const int h0 = wave * 32;
    float ar[2][4];
#pragma unroll
    for (int m = 0; m < 2; ++m)
#pragma unroll
      for (int r = 0; r < 4; ++r) ar[m][r] = aA[m * 16 + quad * 4 + r];
#pragma unroll
    for (int m = 0; m < 2; ++m)
#pragma unroll
      for (int nt = 0; nt < 2; ++nt)
#pragma unroll
        for (int r = 0; r < 4; ++r) oacc[m][nt][r] *= ar[m][r];
#pragma unroll
    for (int ks = 0; ks < 2; ++ks) {
      bf16x8 pa[2];
      pa[0] = *(bf16x8*)&P[ln * 72 + ks * 32 + quad * 8];
      pa[1] = *(bf16x8*)&P[(16 + ln) * 72 + ks * 32 + quad * 8];
#pragma unroll
      for (int nt = 0; nt < 2; ++nt) {
        const int n = h0 + nt * 16 + ln;
        bf16x8 bv = *(bf16x8*)&Vt[cur][n * 64 + (((ks * 4 + quad) ^ (n & 7)) * 8)];
#pragma unroll
        for (int m = 0; m < 2; ++m)
          oacc[m][nt] = __builtin_amdgcn_mfma_f32_16x16x32_bf16(pa[m], bv, oacc[m][nt], 0, 0, 0);
      }
    }
  }

  if (l8 == 0) lL[srow] = l_run;
  __syncthreads();
  const int h0 = wave * 32;
#pragma unroll
  for (int m = 0; m < 2; ++m) {
    float linv[4];
#pragma unroll
    for (int r = 0; r < 4; ++r) linv[r] = 1.f / lL[m * 16 + quad * 4 + r];
#pragma unroll
    for (int nt = 0; nt < 2; ++nt)
#pragma unroll
      for (int r = 0; r < 4; ++r) {
        int row = q0 + m * 16 + quad * 4 + r;
        out[(size_t)(b * T_ + row) * H_ + h0 + nt * 16 + ln] = oacc[m][nt][r] * linv[r];
      }
  }
}

// ---------------------------------------------------------------------------
extern "C" void kernel_launch(void* const* d_in, const int* in_sizes, int n_in,
                              void* d_out, int out_size, void* d_ws, size_t ws_size,
                              hipStream_t stream) {
  const float* x  = (const float*)d_in[0];
  const float* Wq = (const float*)d_in[1];
  const float* Wk = (const float*)d_in[2];
  const float* Wv = (const float*)d_in[3];
  float* out = (float*)d_out;

  char* ws = (char*)d_ws;
  short* qb  = (short*)(ws);                // 4 MB  q  bf16 [BT][128]
  short* kb  = (short*)(ws + 4194304);      // 4 MB  k  bf16 [BT][128]
  short* vtb = (short*)(ws + 8388608);      // 4 MB  v^T bf16 [B][128][T]
  short* Wt  = (short*)(ws + 12582912);     // 0.75 MB  W^T bf16 [3][128][1024]

  wcvt_kernel<<<dim3(D_ / 64, 3), 256, 0, stream>>>(Wq, Wk, Wv, Wt);
  proj_kernel<<<dim3(BT / 128, 3), 256, 0, stream>>>(x, Wt, qb, kb, vtb);
  attn_kernel<<<dim3(8 * 64), 256, 0, stream>>>(qb, kb, vtb, out);
}

// Round 8
// 176.620 us; speedup vs baseline: 1.8351x; 1.0197x over previous
//
#include <hip/hip_runtime.h>
#include <math.h>

#define B_ 8
#define T_ 2048
#define D_ 1024
#define H_ 128
#define BT (B_ * T_)

typedef short bf16x8 __attribute__((ext_vector_type(8)));
typedef float f32x4 __attribute__((ext_vector_type(4)));

static constexpr float SCALE = 0.08838834764831845f;  // 1/sqrt(128)

__device__ inline unsigned short f2b(float f) {
  unsigned int u = __float_as_uint(f);
  u += 0x7FFF + ((u >> 16) & 1);  // RNE
  return (unsigned short)(u >> 16);
}
__device__ inline unsigned int pk2(float a, float b) {
  return (unsigned int)f2b(a) | ((unsigned int)f2b(b) << 16);
}

// global (AS1) -> LDS (AS3) direct 16B copy; dest = wave-uniform base + lane*16
__device__ __forceinline__ void gll16(const void* g, void* l) {
  __builtin_amdgcn_global_load_lds(
      (const __attribute__((address_space(1))) void*)g,
      (__attribute__((address_space(3))) void*)l, 16, 0, 0);
}

// ---------------------------------------------------------------------------
// Setup: W[d][h] fp32 -> Wt[sel][h][d] bf16 through LDS, coalesced stores.
// ---------------------------------------------------------------------------
__global__ __launch_bounds__(256) void wcvt_kernel(
    const float* __restrict__ Wq, const float* __restrict__ Wk,
    const float* __restrict__ Wv, short* __restrict__ Wt) {
  __shared__ short Wls[128 * 72];  // [h][d] bf16, pitch 72
  const int sel = blockIdx.y;
  const float* W = sel == 0 ? Wq : (sel == 1 ? Wk : Wv);
  const int d0 = blockIdx.x * 64;
  const int tid = threadIdx.x;
#pragma unroll
  for (int i = 0; i < 8; ++i) {
    int slot = tid + i * 256;         // 2048 float4 slots: 64 d x 32 h-groups
    int r = slot >> 5, hg = slot & 31;
    float4 w = *(const float4*)(W + (size_t)(d0 + r) * H_ + hg * 4);
    Wls[(hg * 4 + 0) * 72 + r] = (short)f2b(w.x);
    Wls[(hg * 4 + 1) * 72 + r] = (short)f2b(w.y);
    Wls[(hg * 4 + 2) * 72 + r] = (short)f2b(w.z);
    Wls[(hg * 4 + 3) * 72 + r] = (short)f2b(w.w);
  }
  __syncthreads();
  short* dst = Wt + (size_t)sel * D_ * H_;
#pragma unroll
  for (int i = 0; i < 4; ++i) {
    int slot = tid + i * 256;         // 1024 int4 slots: 128 h x 8 d-groups
    int h = slot >> 3, g = slot & 7;
    *(int4*)(dst + (size_t)h * D_ + d0 + g * 8) = *(int4*)&Wls[h * 72 + g * 8];
  }
}

// ---------------------------------------------------------------------------
// Proj: unchanged (128x128 tile, gll W staging, swizzled LDS).
// ---------------------------------------------------------------------------
__global__ __launch_bounds__(256) void proj_kernel(
    const float* __restrict__ x, const short* __restrict__ Wt,
    short* __restrict__ qb, short* __restrict__ kb, short* __restrict__ vtb) {
  __shared__ alignas(16) char smem[36864];
  short* Xs = (short*)smem;             // [128][64] bf16, swizzled
  short* Ws = (short*)(smem + 16384);   // [128][64] bf16, swizzled

  const int tid = threadIdx.x;
  const int wave = tid >> 6, lane = tid & 63;
  const int ln = lane & 15, quad = lane >> 4;
  const int mw = wave & 1, nw = wave >> 1;
  const int sel = blockIdx.y;
  const int row0 = blockIdx.x * 128;
  const short* W = Wt + (size_t)sel * (size_t)(D_ * H_);

  f32x4 acc[4][4];
#pragma unroll
  for (int mi = 0; mi < 4; ++mi)
#pragma unroll
    for (int ni = 0; ni < 4; ++ni) acc[mi][ni] = (f32x4){0.f, 0.f, 0.f, 0.f};

  for (int s = 0; s < 16; ++s) {
    const int k0 = s * 64;
    if (s) __syncthreads();

#pragma unroll
    for (int j = 0; j < 4; ++j) {
      const int rbase = wave * 32 + j * 8;
      const int n = rbase + (lane >> 3);
      const int gp = (lane & 7) ^ (n & 7);
      gll16(W + (size_t)n * D_ + k0 + gp * 8, (char*)Ws + rbase * 128);
    }
    {
      float4 xr[8];
#pragma unroll
      for (int i = 0; i < 8; ++i) {
        int fid = tid + i * 256;
        int r = fid >> 4, g4 = fid & 15;
        xr[i] = *(const float4*)(x + (size_t)(row0 + r) * D_ + k0 + g4 * 4);
      }
#pragma unroll
      for (int i = 0; i < 8; ++i) {
        int fid = tid + i * 256;
        int r = fid >> 4, g4 = fid & 15;
        int g = g4 >> 1, half = g4 & 1;
        unsigned int* p = (unsigned int*)&Xs[r * 64 + ((g ^ (r & 7)) * 8) + half * 4];
        p[0] = pk2(xr[i].x, xr[i].y);
        p[1] = pk2(xr[i].z, xr[i].w);
      }
    }
    __syncthreads();

#pragma unroll
    for (int kk = 0; kk < 2; ++kk) {
      bf16x8 a[4];
#pragma unroll
      for (int mi = 0; mi < 4; ++mi) {
        int r = mw * 64 + mi * 16 + ln;
        int g = kk * 4 + quad;
        a[mi] = *(bf16x8*)&Xs[r * 64 + ((g ^ (r & 7)) * 8)];
      }
#pragma unroll
      for (int ni = 0; ni < 4; ++ni) {
        int n = nw * 64 + ni * 16 + ln;
        int g = kk * 4 + quad;
        bf16x8 bb = *(bf16x8*)&Ws[n * 64 + ((g ^ (n & 7)) * 8)];
#pragma unroll
        for (int mi = 0; mi < 4; ++mi)
          acc[mi][ni] = __builtin_amdgcn_mfma_f32_16x16x32_bf16(a[mi], bb, acc[mi][ni], 0, 0, 0);
      }
    }
  }

  __syncthreads();
  short* Cs = (short*)smem;  // [128][136] bf16
  if (sel < 2) {
    short* out = sel ? kb : qb;
#pragma unroll
    for (int mi = 0; mi < 4; ++mi)
#pragma unroll
      for (int ni = 0; ni < 4; ++ni)
#pragma unroll
        for (int rr = 0; rr < 4; ++rr)
          Cs[(mw * 64 + mi * 16 + quad * 4 + rr) * 136 + nw * 64 + ni * 16 + ln] =
              (short)f2b(acc[mi][ni][rr]);
    __syncthreads();
#pragma unroll
    for (int i = 0; i < 8; ++i) {
      int slot = tid + i * 256;
      int r = slot >> 4, g = slot & 15;
      *(int4*)(out + (size_t)(row0 + r) * H_ + g * 8) = *(int4*)&Cs[r * 136 + g * 8];
    }
  } else {
#pragma unroll
    for (int mi = 0; mi < 4; ++mi)
#pragma unroll
      for (int ni = 0; ni < 4; ++ni)
#pragma unroll
        for (int rr = 0; rr < 4; ++rr)
          Cs[(nw * 64 + ni * 16 + ln) * 136 + mw * 64 + mi * 16 + quad * 4 + rr] =
              (short)f2b(acc[mi][ni][rr]);
    __syncthreads();
    const int b = row0 >> 11, t0 = row0 & 2047;
#pragma unroll
    for (int i = 0; i < 8; ++i) {
      int slot = tid + i * 256;
      int h = slot >> 4, g = slot & 15;
      *(int4*)(vtb + (size_t)(b * H_ + h) * T_ + t0 + g * 8) = *(int4*)&Cs[h * 136 + g * 8];
    }
  }
}

// ---------------------------------------------------------------------------
// Attention, wave-decoupled: S^T = K*Q^T so each wave owns 16 queries and the
// softmax over keys is WAVE-LOCAL (in-register + shfl_xor 16/32). PV computed
// as O^T = V^T * P^T; P^T passes through a wave-PRIVATE LDS scratch (lgkmcnt
// only, no barrier). 2 barriers/chunk (staging only). Block = 128 thr (2
// waves x 16q = 32q tile). K double-buffered via gll; V single-buffered.
// LDS 53.5 KB -> 3 blocks/CU. Epilogue transposes O via freed LDS.
// ---------------------------------------------------------------------------
__global__ __launch_bounds__(128) void attn_kernel(
    const short* __restrict__ qb, const short* __restrict__ kb,
    const short* __restrict__ vtb, float* __restrict__ out) {
  __shared__ alignas(16) char smem[53632];
  short* Ks0 = (short*)smem;              // [64][128] bf16 swizzled, buf 0
  short* Ks1 = (short*)(smem + 16384);    // buf 1
  short* Vt  = (short*)(smem + 32768);    // [128][64] bf16 swizzled (single)
  short* Pt  = (short*)(smem + 49152);    // per-wave [16][68] bf16 scratch

  const int tid = threadIdx.x;
  const int wv = tid >> 6, lane = tid & 63;
  const int ln = lane & 15, quad = lane >> 4;
  const int slot = blockIdx.x & 255;
  const int pass = blockIdx.x >> 8;
  const int b = slot >> 5;
  const int j = slot & 31;
  const int tile = pass ? (63 - j) : j;   // complementary pairing (r7)
  const int q0 = tile * 32;

  short* myP = Pt + wv * (16 * 68);

  // Q fragments (B-operand layout == old A layout): queries q0+wv*16+ln
  bf16x8 qfr[4];
#pragma unroll
  for (int kk = 0; kk < 4; ++kk)
    qfr[kk] = *(const bf16x8*)(qb + (size_t)(b * T_ + q0 + wv * 16 + ln) * H_ +
                               kk * 32 + quad * 8);

  f32x4 oacc[8];  // O^T tiles: [16h x 16q] x 8 -> h=ht*16+quad*4+r, q=ln
#pragma unroll
  for (int ht = 0; ht < 8; ++ht) oacc[ht] = (f32x4){0.f, 0.f, 0.f, 0.f};

  float m_run = -INFINITY, l_run = 0.f;
  const int qglob = q0 + wv * 16 + ln;

  // K chunk stage (64 keys x 256B, swizzled): 8 gll per wave (4 rows each)
  auto stageK = [&](short* dst, int s0) {
#pragma unroll
    for (int jj = 0; jj < 8; ++jj) {
      const int rb = wv * 32 + jj * 4;
      const int r = rb + (lane >> 4);
      const int gp = (lane & 15) ^ (r & 7);
      gll16(kb + (size_t)(b * T_ + s0 + r) * H_ + gp * 8, (char*)dst + rb * 256);
    }
  };
  // V^T chunk stage (128 h x 128B, swizzled): 8 gll per wave (8 rows each)
  auto stageV = [&](int s0) {
#pragma unroll
    for (int jj = 0; jj < 8; ++jj) {
      const int hb = wv * 64 + jj * 8;
      const int h = hb + (lane >> 3);
      const int gp = (lane & 7) ^ (h & 7);
      gll16(vtb + (size_t)(b * H_ + h) * T_ + s0 + gp * 8, (char*)Vt + hb * 128);
    }
  };

  const int nch = (q0 >> 6) + 1;
  stageK(Ks0, 0);  // prologue

  for (int ch = 0; ch < nch; ++ch) {
    const int s0 = ch * 64;
    short* Kc = (ch & 1) ? Ks1 : Ks0;
    __syncthreads();  // K[cur] ready; Vt free (prev PV done everywhere)
    stageV(s0);
    if (ch + 1 < nch) stageK((ch & 1) ? Ks0 : Ks1, s0 + 64);

    // S^T = K * Q^T : 4 key-tiles x 4 kk = 16 MFMAs, all for this wave's 16 q
    f32x4 sacc[4];
#pragma unroll
    for (int t = 0; t < 4; ++t) sacc[t] = (f32x4){0.f, 0.f, 0.f, 0.f};
#pragma unroll
    for (int kk = 0; kk < 4; ++kk) {
#pragma unroll
      for (int t = 0; t < 4; ++t) {
        const int krow = t * 16 + ln;
        bf16x8 kf = *(bf16x8*)&Kc[krow * 128 + (((kk * 4 + quad) ^ (ln & 7)) * 8)];
        sacc[t] = __builtin_amdgcn_mfma_f32_16x16x32_bf16(kf, qfr[kk], sacc[t], 0, 0, 0);
      }
    }

    // wave-local online softmax over keys (rows): in-reg + quad shuffles
    float sv[4][4];
    float mc = -INFINITY;
#pragma unroll
    for (int t = 0; t < 4; ++t)
#pragma unroll
      for (int r = 0; r < 4; ++r) {
        const int key = s0 + t * 16 + quad * 4 + r;
        float s = sacc[t][r] * SCALE;
        sv[t][r] = (key <= qglob) ? s : -INFINITY;
        mc = fmaxf(mc, sv[t][r]);
      }
    mc = fmaxf(mc, __shfl_xor(mc, 16));
    mc = fmaxf(mc, __shfl_xor(mc, 32));
    const float mnew = fmaxf(m_run, mc);
    const float alpha = __expf(m_run - mnew);
    float lc = 0.f;
    float p[4][4];
#pragma unroll
    for (int t = 0; t < 4; ++t)
#pragma unroll
      for (int r = 0; r < 4; ++r) {
        p[t][r] = __expf(sv[t][r] - mnew);
        lc += p[t][r];
      }
    lc += __shfl_xor(lc, 16);
    lc += __shfl_xor(lc, 32);
    l_run = l_run * alpha + lc;
    m_run = mnew;

    // P^T -> wave-private LDS scratch [q=ln][key], pitch 68 shorts
#pragma unroll
    for (int t = 0; t < 4; ++t) {
      *(unsigned int*)&myP[ln * 68 + t * 16 + quad * 4 + 0] = pk2(p[t][0], p[t][1]);
      *(unsigned int*)&myP[ln * 68 + t * 16 + quad * 4 + 2] = pk2(p[t][2], p[t][3]);
    }
#pragma unroll
    for (int ht = 0; ht < 8; ++ht)
#pragma unroll
      for (int r = 0; r < 4; ++r) oacc[ht][r] *= alpha;

    __syncthreads();  // V staged by BOTH waves must be visible (drains gll)

    // O^T += V^T * P^T : 8 h-tiles x 2 kk = 16 MFMAs
#pragma unroll
    for (int kk2 = 0; kk2 < 2; ++kk2) {
      bf16x8 pf = *(bf16x8*)&myP[ln * 68 + kk2 * 32 + quad * 8];
#pragma unroll
      for (int ht = 0; ht < 8; ++ht) {
        const int hrow = ht * 16 + ln;
        bf16x8 vf = *(bf16x8*)&Vt[hrow * 64 + (((kk2 * 4 + quad) ^ (ln & 7)) * 8)];
        oacc[ht] = __builtin_amdgcn_mfma_f32_16x16x32_bf16(vf, pf, oacc[ht], 0, 0, 0);
      }
    }
  }

  // epilogue: divide by l (per-lane = per-query), transpose via freed LDS
  const float linv = 1.0f / l_run;
#pragma unroll
  for (int ht = 0; ht < 8; ++ht)
#pragma unroll
    for (int r = 0; r < 4; ++r) oacc[ht][r] *= linv;

  __syncthreads();  // everyone done with Ks/Vt
  float* Ot = (float*)smem;  // [32][132] f32 = 16.9 KB
#pragma unroll
  for (int ht = 0; ht < 8; ++ht) {
    double2* dst = (double2*)&Ot[(wv * 16 + ln) * 132 + ht * 16 + quad * 4];
    *(double2*)dst = *(double2*)&oacc[ht];  // 4 f32 = 16B
  }
  __syncthreads();
#pragma unroll
  for (int i = 0; i < 8; ++i) {
    int slot2 = tid + i * 128;          // 1024 float4 slots: 32 rows x 32
    int r = slot2 >> 5, c = slot2 & 31;
    float4 v = *(float4*)&Ot[r * 132 + c * 4];
    *(float4*)(out + (size_t)(b * T_ + q0 + r) * H_ + c * 4) = v;
  }
}

// ---------------------------------------------------------------------------
extern "C" void kernel_launch(void* const* d_in, const int* in_sizes, int n_in,
                              void* d_out, int out_size, void* d_ws, size_t ws_size,
                              hipStream_t stream) {
  const float* x  = (const float*)d_in[0];
  const float* Wq = (const float*)d_in[1];
  const float* Wk = (const float*)d_in[2];
  const float* Wv = (const float*)d_in[3];
  float* out = (float*)d_out;

  char* ws = (char*)d_ws;
  short* qb  = (short*)(ws);                // 4 MB  q  bf16 [BT][128]
  short* kb  = (short*)(ws + 4194304);      // 4 MB  k  bf16 [BT][128]
  short* vtb = (short*)(ws + 8388608);      // 4 MB  v^T bf16 [B][128][T]
  short* Wt  = (short*)(ws + 12582912);     // 0.75 MB  W^T bf16 [3][128][1024]

  wcvt_kernel<<<dim3(D_ / 64, 3), 256, 0, stream>>>(Wq, Wk, Wv, Wt);
  proj_kernel<<<dim3(BT / 128, 3), 256, 0, stream>>>(x, Wt, qb, kb, vtb);
  attn_kernel<<<dim3(512), 128, 0, stream>>>(qb, kb, vtb, out);
}

// Round 10
// 172.359 us; speedup vs baseline: 1.8805x; 1.0247x over previous
//
#include <hip/hip_runtime.h>
#include <math.h>

#define B_ 8
#define T_ 2048
#define D_ 1024
#define H_ 128
#define BT (B_ * T_)

typedef short bf16x8 __attribute__((ext_vector_type(8)));
typedef float f32x4 __attribute__((ext_vector_type(4)));

static constexpr float SCALE = 0.08838834764831845f;  // 1/sqrt(128)

__device__ inline unsigned short f2b(float f) {
  unsigned int u = __float_as_uint(f);
  u += 0x7FFF + ((u >> 16) & 1);  // RNE
  return (unsigned short)(u >> 16);
}
__device__ inline unsigned int pk2(float a, float b) {
  return (unsigned int)f2b(a) | ((unsigned int)f2b(b) << 16);
}

// global (AS1) -> LDS (AS3) direct 16B copy; dest = wave-uniform base + lane*16
__device__ __forceinline__ void gll16(const void* g, void* l) {
  __builtin_amdgcn_global_load_lds(
      (const __attribute__((address_space(1))) void*)g,
      (__attribute__((address_space(3))) void*)l, 16, 0, 0);
}

// ---------------------------------------------------------------------------
// Setup: W[d][h] fp32 -> Wt[sel][h][d] bf16 through LDS, coalesced stores.
// ---------------------------------------------------------------------------
__global__ __launch_bounds__(256) void wcvt_kernel(
    const float* __restrict__ Wq, const float* __restrict__ Wk,
    const float* __restrict__ Wv, short* __restrict__ Wt) {
  __shared__ short Wls[128 * 72];  // [h][d] bf16, pitch 72
  const int sel = blockIdx.y;
  const float* W = sel == 0 ? Wq : (sel == 1 ? Wk : Wv);
  const int d0 = blockIdx.x * 64;
  const int tid = threadIdx.x;
#pragma unroll
  for (int i = 0; i < 8; ++i) {
    int slot = tid + i * 256;         // 2048 float4 slots: 64 d x 32 h-groups
    int r = slot >> 5, hg = slot & 31;
    float4 w = *(const float4*)(W + (size_t)(d0 + r) * H_ + hg * 4);
    Wls[(hg * 4 + 0) * 72 + r] = (short)f2b(w.x);
    Wls[(hg * 4 + 1) * 72 + r] = (short)f2b(w.y);
    Wls[(hg * 4 + 2) * 72 + r] = (short)f2b(w.z);
    Wls[(hg * 4 + 3) * 72 + r] = (short)f2b(w.w);
  }
  __syncthreads();
  short* dst = Wt + (size_t)sel * D_ * H_;
#pragma unroll
  for (int i = 0; i < 4; ++i) {
    int slot = tid + i * 256;         // 1024 int4 slots: 128 h x 8 d-groups
    int h = slot >> 3, g = slot & 7;
    *(int4*)(dst + (size_t)h * D_ + d0 + g * 8) = *(int4*)&Wls[h * 72 + g * 8];
  }
}

// ---------------------------------------------------------------------------
// Proj: C = X*W, bf16 MFMA. 64 rows x 128 cols per block -> grid 768 = exactly
// 3 blocks/CU. Double-buffered stages, ONE barrier per stage: barrier ->
// issue next stage (W via gll, X via short-live-range regs) -> compute
// current. Swizzled unpadded LDS rows. Buffer selection via TERNARY (const
// arrays of LDS pointers fail to compile on gfx950 — round-9 lesson).
// ---------------------------------------------------------------------------
__global__ __launch_bounds__(256) void proj_kernel(
    const float* __restrict__ x, const short* __restrict__ Wt,
    short* __restrict__ qb, short* __restrict__ kb, short* __restrict__ vtb) {
  __shared__ alignas(16) char smem[49152];
  short* Xs0 = (short*)smem;             // [64][64] bf16 swizzled
  short* Xs1 = (short*)(smem + 8192);
  short* Ws0 = (short*)(smem + 16384);   // [128][64] bf16 swizzled
  short* Ws1 = (short*)(smem + 32768);

  const int tid = threadIdx.x;
  const int wave = tid >> 6, lane = tid & 63;
  const int ln = lane & 15, quad = lane >> 4;
  const int mw = wave & 1, nw = wave >> 1;  // wave tile: 32 rows x 64 cols
  const int sel = blockIdx.y;
  const int row0 = blockIdx.x * 64;
  const short* W = Wt + (size_t)sel * (size_t)(D_ * H_);

  f32x4 acc[2][4];
#pragma unroll
  for (int mi = 0; mi < 2; ++mi)
#pragma unroll
    for (int ni = 0; ni < 4; ++ni) acc[mi][ni] = (f32x4){0.f, 0.f, 0.f, 0.f};

  auto stage = [&](int bf, int k0) {
    short* Ws = bf ? Ws1 : Ws0;
    // W 128x64 via gll: per wave 32 rows, 4 issues x (8 rows x 128B)
#pragma unroll
    for (int j = 0; j < 4; ++j) {
      const int rbase = wave * 32 + j * 8;
      const int n = rbase + (lane >> 3);
      const int gp = (lane & 7) ^ (n & 7);
      gll16(W + (size_t)n * D_ + k0 + gp * 8, (char*)Ws + rbase * 128);
    }
    // X 64x64 fp32 -> bf16, swizzled (short live ranges)
    short* Xs = bf ? Xs1 : Xs0;
    float4 xr[4];
#pragma unroll
    for (int i = 0; i < 4; ++i) {
      int fid = tid + i * 256;           // 1024 float4 slots: 64 rows x 16
      int r = fid >> 4, g4 = fid & 15;
      xr[i] = *(const float4*)(x + (size_t)(row0 + r) * D_ + k0 + g4 * 4);
    }
#pragma unroll
    for (int i = 0; i < 4; ++i) {
      int fid = tid + i * 256;
      int r = fid >> 4, g4 = fid & 15;
      int g = g4 >> 1, half = g4 & 1;
      unsigned int* p = (unsigned int*)&Xs[r * 64 + ((g ^ (r & 7)) * 8) + half * 4];
      p[0] = pk2(xr[i].x, xr[i].y);
      p[1] = pk2(xr[i].z, xr[i].w);
    }
  };

  stage(0, 0);  // prologue
  for (int s = 0; s < 16; ++s) {
    __syncthreads();  // drains buf[s&1] (gll + ds_write); prev compute done
    if (s < 15) stage((s + 1) & 1, (s + 1) * 64);
    const short* Xs = (s & 1) ? Xs1 : Xs0;
    const short* Ws = (s & 1) ? Ws1 : Ws0;
#pragma unroll
    for (int kk = 0; kk < 2; ++kk) {
      bf16x8 a[2];
#pragma unroll
      for (int mi = 0; mi < 2; ++mi) {
        int r = mw * 32 + mi * 16 + ln;
        a[mi] = *(bf16x8*)&Xs[r * 64 + (((kk * 4 + quad) ^ (r & 7)) * 8)];
      }
#pragma unroll
      for (int ni = 0; ni < 4; ++ni) {
        int n = nw * 64 + ni * 16 + ln;
        bf16x8 bb = *(bf16x8*)&Ws[n * 64 + (((kk * 4 + quad) ^ (n & 7)) * 8)];
#pragma unroll
        for (int mi = 0; mi < 2; ++mi)
          acc[mi][ni] = __builtin_amdgcn_mfma_f32_16x16x32_bf16(a[mi], bb, acc[mi][ni], 0, 0, 0);
      }
    }
  }

  __syncthreads();  // tiles dead; reuse smem for epilogue repack
  short* Cs = (short*)smem;
  if (sel < 2) {
    short* out = sel ? kb : qb;
    // frags -> Cs[64][136] row-major (17.4 KB)
#pragma unroll
    for (int mi = 0; mi < 2; ++mi)
#pragma unroll
      for (int ni = 0; ni < 4; ++ni)
#pragma unroll
        for (int rr = 0; rr < 4; ++rr)
          Cs[(mw * 32 + mi * 16 + quad * 4 + rr) * 136 + nw * 64 + ni * 16 + ln] =
              (short)f2b(acc[mi][ni][rr]);
    __syncthreads();
#pragma unroll
    for (int i = 0; i < 4; ++i) {
      int slot = tid + i * 256;          // 1024 int4 slots: 64 rows x 16
      int r = slot >> 4, g = slot & 15;
      *(int4*)(out + (size_t)(row0 + r) * H_ + g * 8) = *(int4*)&Cs[r * 136 + g * 8];
    }
  } else {
    // transpose -> Cs[128 h][72 t] (18.4 KB), write vt[b][h][t] coalesced
#pragma unroll
    for (int mi = 0; mi < 2; ++mi)
#pragma unroll
      for (int ni = 0; ni < 4; ++ni)
#pragma unroll
        for (int rr = 0; rr < 4; ++rr)
          Cs[(nw * 64 + ni * 16 + ln) * 72 + mw * 32 + mi * 16 + quad * 4 + rr] =
              (short)f2b(acc[mi][ni][rr]);
    __syncthreads();
    const int b = row0 >> 11, t0 = row0 & 2047;
#pragma unroll
    for (int i = 0; i < 4; ++i) {
      int slot = tid + i * 256;          // 1024 int4 slots: 128 h x 8
      int h = slot >> 3, g = slot & 7;
      *(int4*)(vtb + (size_t)(b * H_ + h) * T_ + t0 + g * 8) = *(int4*)&Cs[h * 72 + g * 8];
    }
  }
}

// ---------------------------------------------------------------------------
// Attention, wave-decoupled + FULLY double-buffered K and V, ONE barrier per
// chunk: barrier -> issue gll for chunk ch+1 -> compute chunk ch. Every gll
// has a full chunk of compute to land. S^T = K*Q^T (wave-local softmax),
// O^T = V^T*P^T with wave-private P scratch (lgkm-ordered, no barrier).
// LDS 69.9 KB -> 2 blocks/CU. Complementary tile pairing kept.
// ---------------------------------------------------------------------------
__global__ __launch_bounds__(128) void attn_kernel(
    const short* __restrict__ qb, const short* __restrict__ kb,
    const short* __restrict__ vtb, float* __restrict__ out) {
  __shared__ alignas(16) char smem[69888];
  short* Ks0 = (short*)smem;               // [64][128] bf16 swizzled
  short* Ks1 = (short*)(smem + 16384);
  short* Vt0 = (short*)(smem + 32768);     // [128][64] bf16 swizzled
  short* Vt1 = (short*)(smem + 49152);
  short* Pt  = (short*)(smem + 65536);     // 2 waves x [16][68] bf16

  const int tid = threadIdx.x;
  const int wv = tid >> 6, lane = tid & 63;
  const int ln = lane & 15, quad = lane >> 4;
  const int slot = blockIdx.x & 255;
  const int pass = blockIdx.x >> 8;
  const int b = slot >> 5;
  const int j = slot & 31;
  const int tile = pass ? (63 - j) : j;   // complementary pairing
  const int q0 = tile * 32;

  short* myP = Pt + wv * (16 * 68);

  bf16x8 qfr[4];  // this wave's 16 queries, B-operand layout
#pragma unroll
  for (int kk = 0; kk < 4; ++kk)
    qfr[kk] = *(const bf16x8*)(qb + (size_t)(b * T_ + q0 + wv * 16 + ln) * H_ +
                               kk * 32 + quad * 8);

  f32x4 oacc[8];  // O^T: h = ht*16+quad*4+r, q = ln
#pragma unroll
  for (int ht = 0; ht < 8; ++ht) oacc[ht] = (f32x4){0.f, 0.f, 0.f, 0.f};

  float m_run = -INFINITY, l_run = 0.f;
  const int qglob = q0 + wv * 16 + ln;

  auto stageK = [&](short* dst, int s0) {
#pragma unroll
    for (int jj = 0; jj < 8; ++jj) {
      const int rb = wv * 32 + jj * 4;
      const int r = rb + (lane >> 4);
      const int gp = (lane & 15) ^ (r & 7);
      gll16(kb + (size_t)(b * T_ + s0 + r) * H_ + gp * 8, (char*)dst + rb * 256);
    }
  };
  auto stageV = [&](short* dst, int s0) {
#pragma unroll
    for (int jj = 0; jj < 8; ++jj) {
      const int hb = wv * 64 + jj * 8;
      const int h = hb + (lane >> 3);
      const int gp = (lane & 7) ^ (h & 7);
      gll16(vtb + (size_t)(b * H_ + h) * T_ + s0 + gp * 8, (char*)dst + hb * 128);
    }
  };

  const int nch = (q0 >> 6) + 1;
  stageK(Ks0, 0);  // prologue: chunk 0
  stageV(Vt0, 0);

  for (int ch = 0; ch < nch; ++ch) {
    const int s0 = ch * 64;
    const int cur = ch & 1;
    // ONE barrier: drains chunk-ch gll (issued a full chunk ago) and ensures
    // all waves finished reading the other buffer before restaging it.
    __syncthreads();
    if (ch + 1 < nch) {
      stageK(cur ? Ks0 : Ks1, s0 + 64);
      stageV(cur ? Vt0 : Vt1, s0 + 64);
    }
    const short* Kc = cur ? Ks1 : Ks0;
    const short* Vc = cur ? Vt1 : Vt0;

    // S^T = K * Q^T : 4 key-tiles x 4 kk = 16 MFMAs
    f32x4 sacc[4];
#pragma unroll
    for (int t = 0; t < 4; ++t) sacc[t] = (f32x4){0.f, 0.f, 0.f, 0.f};
#pragma unroll
    for (int kk = 0; kk < 4; ++kk) {
#pragma unroll
      for (int t = 0; t < 4; ++t) {
        const int krow = t * 16 + ln;
        bf16x8 kf = *(bf16x8*)&Kc[krow * 128 + (((kk * 4 + quad) ^ (ln & 7)) * 8)];
        sacc[t] = __builtin_amdgcn_mfma_f32_16x16x32_bf16(kf, qfr[kk], sacc[t], 0, 0, 0);
      }
    }

    // wave-local online softmax over keys
    float sv[4][4];
    float mc = -INFINITY;
#pragma unroll
    for (int t = 0; t < 4; ++t)
#pragma unroll
      for (int r = 0; r < 4; ++r) {
        const int key = s0 + t * 16 + quad * 4 + r;
        float s = sacc[t][r] * SCALE;
        sv[t][r] = (key <= qglob) ? s : -INFINITY;
        mc = fmaxf(mc, sv[t][r]);
      }
    mc = fmaxf(mc, __shfl_xor(mc, 16));
    mc = fmaxf(mc, __shfl_xor(mc, 32));
    const float mnew = fmaxf(m_run, mc);
    const float alpha = __expf(m_run - mnew);
    float lc = 0.f;
    float p[4][4];
#pragma unroll
    for (int t = 0; t < 4; ++t)
#pragma unroll
      for (int r = 0; r < 4; ++r) {
        p[t][r] = __expf(sv[t][r] - mnew);
        lc += p[t][r];
      }
    lc += __shfl_xor(lc, 16);
    lc += __shfl_xor(lc, 32);
    l_run = l_run * alpha + lc;
    m_run = mnew;

    // P^T -> wave-private LDS scratch (lgkm-ordered; no barrier needed)
#pragma unroll
    for (int t = 0; t < 4; ++t) {
      *(unsigned int*)&myP[ln * 68 + t * 16 + quad * 4 + 0] = pk2(p[t][0], p[t][1]);
      *(unsigned int*)&myP[ln * 68 + t * 16 + quad * 4 + 2] = pk2(p[t][2], p[t][3]);
    }
#pragma unroll
    for (int ht = 0; ht < 8; ++ht)
#pragma unroll
      for (int r = 0; r < 4; ++r) oacc[ht][r] *= alpha;

    // O^T += V^T * P^T : 8 h-tiles x 2 kk = 16 MFMAs (V staged a chunk ago)
#pragma unroll
    for (int kk2 = 0; kk2 < 2; ++kk2) {
      bf16x8 pf = *(bf16x8*)&myP[ln * 68 + kk2 * 32 + quad * 8];
#pragma unroll
      for (int ht = 0; ht < 8; ++ht) {
        const int hrow = ht * 16 + ln;
        bf16x8 vf = *(bf16x8*)&Vc[hrow * 64 + (((kk2 * 4 + quad) ^ (ln & 7)) * 8)];
        oacc[ht] = __builtin_amdgcn_mfma_f32_16x16x32_bf16(vf, pf, oacc[ht], 0, 0, 0);
      }
    }
  }

  // epilogue: divide by l, transpose via freed LDS, coalesced f32 stores
  const float linv = 1.0f / l_run;
#pragma unroll
  for (int ht = 0; ht < 8; ++ht)
#pragma unroll
    for (int r = 0; r < 4; ++r) oacc[ht][r] *= linv;

  __syncthreads();
  float* Ot = (float*)smem;  // [32][132] f32 = 16.9 KB
#pragma unroll
  for (int ht = 0; ht < 8; ++ht)
    *(f32x4*)&Ot[(wv * 16 + ln) * 132 + ht * 16 + quad * 4] = oacc[ht];
  __syncthreads();
#pragma unroll
  for (int i = 0; i < 8; ++i) {
    int slot2 = tid + i * 128;           // 1024 float4 slots: 32 rows x 32
    int r = slot2 >> 5, c = slot2 & 31;
    float4 v = *(float4*)&Ot[r * 132 + c * 4];
    *(float4*)(out + (size_t)(b * T_ + q0 + r) * H_ + c * 4) = v;
  }
}

// ---------------------------------------------------------------------------
extern "C" void kernel_launch(void* const* d_in, const int* in_sizes, int n_in,
                              void* d_out, int out_size, void* d_ws, size_t ws_size,
                              hipStream_t stream) {
  const float* x  = (const float*)d_in[0];
  const float* Wq = (const float*)d_in[1];
  const float* Wk = (const float*)d_in[2];
  const float* Wv = (const float*)d_in[3];
  float* out = (float*)d_out;

  char* ws = (char*)d_ws;
  short* qb  = (short*)(ws);                // 4 MB  q  bf16 [BT][128]
  short* kb  = (short*)(ws + 4194304);      // 4 MB  k  bf16 [BT][128]
  short* vtb = (short*)(ws + 8388608);      // 4 MB  v^T bf16 [B][128][T]
  short* Wt  = (short*)(ws + 12582912);     // 0.75 MB  W^T bf16 [3][128][1024]

  wcvt_kernel<<<dim3(D_ / 64, 3), 256, 0, stream>>>(Wq, Wk, Wv, Wt);
  proj_kernel<<<dim3(BT / 64, 3), 256, 0, stream>>>(x, Wt, qb, kb, vtb);
  attn_kernel<<<dim3(512), 128, 0, stream>>>(qb, kb, vtb, out);
}

// Round 11
// 165.681 us; speedup vs baseline: 1.9563x; 1.0403x over previous
//
#include <hip/hip_runtime.h>
#include <math.h>

#define B_ 8
#define T_ 2048
#define D_ 1024
#define H_ 128
#define BT (B_ * T_)

typedef short bf16x8 __attribute__((ext_vector_type(8)));
typedef float f32x4 __attribute__((ext_vector_type(4)));

static constexpr float SCALE = 0.08838834764831845f;  // 1/sqrt(128)

__device__ inline unsigned short f2b(float f) {
  unsigned int u = __float_as_uint(f);
  u += 0x7FFF + ((u >> 16) & 1);  // RNE
  return (unsigned short)(u >> 16);
}
__device__ inline unsigned int pk2(float a, float b) {
  return (unsigned int)f2b(a) | ((unsigned int)f2b(b) << 16);
}

// global (AS1) -> LDS (AS3) direct 16B copy; dest = wave-uniform base + lane*16
__device__ __forceinline__ void gll16(const void* g, void* l) {
  __builtin_amdgcn_global_load_lds(
      (const __attribute__((address_space(1))) void*)g,
      (__attribute__((address_space(3))) void*)l, 16, 0, 0);
}

// ---------------------------------------------------------------------------
// Setup: W[d][h] fp32 -> Wt[sel][h][d] bf16 through LDS, coalesced stores.
// ---------------------------------------------------------------------------
__global__ __launch_bounds__(256) void wcvt_kernel(
    const float* __restrict__ Wq, const float* __restrict__ Wk,
    const float* __restrict__ Wv, short* __restrict__ Wt) {
  __shared__ short Wls[128 * 72];  // [h][d] bf16, pitch 72
  const int sel = blockIdx.y;
  const float* W = sel == 0 ? Wq : (sel == 1 ? Wk : Wv);
  const int d0 = blockIdx.x * 64;
  const int tid = threadIdx.x;
#pragma unroll
  for (int i = 0; i < 8; ++i) {
    int slot = tid + i * 256;         // 2048 float4 slots: 64 d x 32 h-groups
    int r = slot >> 5, hg = slot & 31;
    float4 w = *(const float4*)(W + (size_t)(d0 + r) * H_ + hg * 4);
    Wls[(hg * 4 + 0) * 72 + r] = (short)f2b(w.x);
    Wls[(hg * 4 + 1) * 72 + r] = (short)f2b(w.y);
    Wls[(hg * 4 + 2) * 72 + r] = (short)f2b(w.z);
    Wls[(hg * 4 + 3) * 72 + r] = (short)f2b(w.w);
  }
  __syncthreads();
  short* dst = Wt + (size_t)sel * D_ * H_;
#pragma unroll
  for (int i = 0; i < 4; ++i) {
    int slot = tid + i * 256;         // 1024 int4 slots: 128 h x 8 d-groups
    int h = slot >> 3, g = slot & 7;
    *(int4*)(dst + (size_t)h * D_ + d0 + g * 8) = *(int4*)&Wls[h * 72 + g * 8];
  }
}

// ---------------------------------------------------------------------------
// Proj: unchanged from round 10 (64x128 tile, dbuf single-barrier staging).
// ---------------------------------------------------------------------------
__global__ __launch_bounds__(256) void proj_kernel(
    const float* __restrict__ x, const short* __restrict__ Wt,
    short* __restrict__ qb, short* __restrict__ kb, short* __restrict__ vtb) {
  __shared__ alignas(16) char smem[49152];
  short* Xs0 = (short*)smem;             // [64][64] bf16 swizzled
  short* Xs1 = (short*)(smem + 8192);
  short* Ws0 = (short*)(smem + 16384);   // [128][64] bf16 swizzled
  short* Ws1 = (short*)(smem + 32768);

  const int tid = threadIdx.x;
  const int wave = tid >> 6, lane = tid & 63;
  const int ln = lane & 15, quad = lane >> 4;
  const int mw = wave & 1, nw = wave >> 1;  // wave tile: 32 rows x 64 cols
  const int sel = blockIdx.y;
  const int row0 = blockIdx.x * 64;
  const short* W = Wt + (size_t)sel * (size_t)(D_ * H_);

  f32x4 acc[2][4];
#pragma unroll
  for (int mi = 0; mi < 2; ++mi)
#pragma unroll
    for (int ni = 0; ni < 4; ++ni) acc[mi][ni] = (f32x4){0.f, 0.f, 0.f, 0.f};

  auto stage = [&](int bf, int k0) {
    short* Ws = bf ? Ws1 : Ws0;
#pragma unroll
    for (int j = 0; j < 4; ++j) {
      const int rbase = wave * 32 + j * 8;
      const int n = rbase + (lane >> 3);
      const int gp = (lane & 7) ^ (n & 7);
      gll16(W + (size_t)n * D_ + k0 + gp * 8, (char*)Ws + rbase * 128);
    }
    short* Xs = bf ? Xs1 : Xs0;
    float4 xr[4];
#pragma unroll
    for (int i = 0; i < 4; ++i) {
      int fid = tid + i * 256;           // 1024 float4 slots: 64 rows x 16
      int r = fid >> 4, g4 = fid & 15;
      xr[i] = *(const float4*)(x + (size_t)(row0 + r) * D_ + k0 + g4 * 4);
    }
#pragma unroll
    for (int i = 0; i < 4; ++i) {
      int fid = tid + i * 256;
      int r = fid >> 4, g4 = fid & 15;
      int g = g4 >> 1, half = g4 & 1;
      unsigned int* p = (unsigned int*)&Xs[r * 64 + ((g ^ (r & 7)) * 8) + half * 4];
      p[0] = pk2(xr[i].x, xr[i].y);
      p[1] = pk2(xr[i].z, xr[i].w);
    }
  };

  stage(0, 0);  // prologue
  for (int s = 0; s < 16; ++s) {
    __syncthreads();  // drains buf[s&1] (gll + ds_write); prev compute done
    if (s < 15) stage((s + 1) & 1, (s + 1) * 64);
    const short* Xs = (s & 1) ? Xs1 : Xs0;
    const short* Ws = (s & 1) ? Ws1 : Ws0;
#pragma unroll
    for (int kk = 0; kk < 2; ++kk) {
      bf16x8 a[2];
#pragma unroll
      for (int mi = 0; mi < 2; ++mi) {
        int r = mw * 32 + mi * 16 + ln;
        a[mi] = *(bf16x8*)&Xs[r * 64 + (((kk * 4 + quad) ^ (r & 7)) * 8)];
      }
#pragma unroll
      for (int ni = 0; ni < 4; ++ni) {
        int n = nw * 64 + ni * 16 + ln;
        bf16x8 bb = *(bf16x8*)&Ws[n * 64 + (((kk * 4 + quad) ^ (n & 7)) * 8)];
#pragma unroll
        for (int mi = 0; mi < 2; ++mi)
          acc[mi][ni] = __builtin_amdgcn_mfma_f32_16x16x32_bf16(a[mi], bb, acc[mi][ni], 0, 0, 0);
      }
    }
  }

  __syncthreads();  // tiles dead; reuse smem for epilogue repack
  short* Cs = (short*)smem;
  if (sel < 2) {
    short* out = sel ? kb : qb;
#pragma unroll
    for (int mi = 0; mi < 2; ++mi)
#pragma unroll
      for (int ni = 0; ni < 4; ++ni)
#pragma unroll
        for (int rr = 0; rr < 4; ++rr)
          Cs[(mw * 32 + mi * 16 + quad * 4 + rr) * 136 + nw * 64 + ni * 16 + ln] =
              (short)f2b(acc[mi][ni][rr]);
    __syncthreads();
#pragma unroll
    for (int i = 0; i < 4; ++i) {
      int slot = tid + i * 256;          // 1024 int4 slots: 64 rows x 16
      int r = slot >> 4, g = slot & 15;
      *(int4*)(out + (size_t)(row0 + r) * H_ + g * 8) = *(int4*)&Cs[r * 136 + g * 8];
    }
  } else {
#pragma unroll
    for (int mi = 0; mi < 2; ++mi)
#pragma unroll
      for (int ni = 0; ni < 4; ++ni)
#pragma unroll
        for (int rr = 0; rr < 4; ++rr)
          Cs[(nw * 64 + ni * 16 + ln) * 72 + mw * 32 + mi * 16 + quad * 4 + rr] =
              (short)f2b(acc[mi][ni][rr]);
    __syncthreads();
    const int b = row0 >> 11, t0 = row0 & 2047;
#pragma unroll
    for (int i = 0; i < 4; ++i) {
      int slot = tid + i * 256;          // 1024 int4 slots: 128 h x 8
      int h = slot >> 3, g = slot & 7;
      *(int4*)(vtb + (size_t)(b * H_ + h) * T_ + t0 + g * 8) = *(int4*)&Cs[h * 72 + g * 8];
    }
  }
}

// ---------------------------------------------------------------------------
// Attention part 1: key-split flash attention partials.
// 256 thr (4 waves), 64 queries/block (wave-decoupled: each wave owns 16 q).
// Key range split into segments of <=8 chunks (512 keys); each segment block
// writes partial O^T (un-normalized), m, l to workspace. 640 blocks, heavy
// segments launched first. K/V double-buffered gll, one barrier per chunk.
// LDS 74.2 KB -> 2 blocks/CU = 8 waves/CU = 2 chains/SIMD (the round-10
// bottleneck was 1 wave/SIMD: all latency exposed).
// ---------------------------------------------------------------------------
__global__ __launch_bounds__(256) void attn_part(
    const short* __restrict__ qb, const short* __restrict__ kb,
    const short* __restrict__ vtb, float* __restrict__ po,
    float* __restrict__ pm, float* __restrict__ pl) {
  __shared__ alignas(16) char smem[74240];
  short* Ks0 = (short*)smem;               // [64][128] bf16 swizzled
  short* Ks1 = (short*)(smem + 16384);
  short* Vt0 = (short*)(smem + 32768);     // [128][64] bf16 swizzled
  short* Vt1 = (short*)(smem + 49152);
  short* Pt  = (short*)(smem + 65536);     // 4 waves x [16][68] bf16

  const int tid = threadIdx.x;
  const int wv = tid >> 6, lane = tid & 63;
  const int ln = lane & 15, quad = lane >> 4;
  const int b = blockIdx.x / 80;
  const int rr = 79 - (blockIdx.x % 80);   // heavy segments first
  // decode rr -> (j, s):  group g = j>>3 has nseg g+1; cum base 4g(g+1)
  const int g = (rr >= 48) ? 3 : (rr >= 24) ? 2 : (rr >= 8) ? 1 : 0;
  const int local = rr - 4 * g * (g + 1);
  const int j = 8 * g + local / (g + 1);
  const int s = local - (local / (g + 1)) * (g + 1);
  const int sid = b * 80 + rr;             // partial storage slot
  const int q0 = j * 64;
  const int nchunks = min(8, j + 1 - 8 * s);

  short* myP = Pt + wv * (16 * 68);

  bf16x8 qfr[4];  // this wave's 16 queries, B-operand layout
#pragma unroll
  for (int kk = 0; kk < 4; ++kk)
    qfr[kk] = *(const bf16x8*)(qb + (size_t)(b * T_ + q0 + wv * 16 + ln) * H_ +
                               kk * 32 + quad * 8);

  f32x4 oacc[8];  // O^T: h = ht*16+quad*4+r, q = ln
#pragma unroll
  for (int ht = 0; ht < 8; ++ht) oacc[ht] = (f32x4){0.f, 0.f, 0.f, 0.f};

  float m_run = -INFINITY, l_run = 0.f;
  const int qglob = q0 + wv * 16 + ln;

  auto stageK = [&](short* dst, int s0) {
#pragma unroll
    for (int jj = 0; jj < 4; ++jj) {
      const int rb = wv * 16 + jj * 4;       // 16 rows per wave
      const int r = rb + (lane >> 4);
      const int gp = (lane & 15) ^ (r & 7);
      gll16(kb + (size_t)(b * T_ + s0 + r) * H_ + gp * 8, (char*)dst + rb * 256);
    }
  };
  auto stageV = [&](short* dst, int s0) {
#pragma unroll
    for (int jj = 0; jj < 4; ++jj) {
      const int hb = wv * 32 + jj * 8;       // 32 rows per wave
      const int h = hb + (lane >> 3);
      const int gp = (lane & 7) ^ (h & 7);
      gll16(vtb + (size_t)(b * H_ + h) * T_ + s0 + gp * 8, (char*)dst + hb * 128);
    }
  };

  stageK(Ks0, 8 * s * 64);  // prologue: first chunk of this segment
  stageV(Vt0, 8 * s * 64);

  for (int ch = 0; ch < nchunks; ++ch) {
    const int s0 = (8 * s + ch) * 64;
    const int cur = ch & 1;
    __syncthreads();  // drains gll for buf[cur]; other buffer free to restage
    if (ch + 1 < nchunks) {
      stageK(cur ? Ks0 : Ks1, s0 + 64);
      stageV(cur ? Vt0 : Vt1, s0 + 64);
    }
    const short* Kc = cur ? Ks1 : Ks0;
    const short* Vc = cur ? Vt1 : Vt0;

    // S^T = K * Q^T : 4 key-tiles x 4 kk = 16 MFMAs (per wave, its 16 q)
    f32x4 sacc[4];
#pragma unroll
    for (int t = 0; t < 4; ++t) sacc[t] = (f32x4){0.f, 0.f, 0.f, 0.f};
#pragma unroll
    for (int kk = 0; kk < 4; ++kk) {
#pragma unroll
      for (int t = 0; t < 4; ++t) {
        const int krow = t * 16 + ln;
        bf16x8 kf = *(bf16x8*)&Kc[krow * 128 + (((kk * 4 + quad) ^ (ln & 7)) * 8)];
        sacc[t] = __builtin_amdgcn_mfma_f32_16x16x32_bf16(kf, qfr[kk], sacc[t], 0, 0, 0);
      }
    }

    // wave-local online softmax over keys
    float sv[4][4];
    float mc = -INFINITY;
#pragma unroll
    for (int t = 0; t < 4; ++t)
#pragma unroll
      for (int r = 0; r < 4; ++r) {
        const int key = s0 + t * 16 + quad * 4 + r;
        float sc = sacc[t][r] * SCALE;
        sv[t][r] = (key <= qglob) ? sc : -INFINITY;
        mc = fmaxf(mc, sv[t][r]);
      }
    mc = fmaxf(mc, __shfl_xor(mc, 16));
    mc = fmaxf(mc, __shfl_xor(mc, 32));
    const float mnew = fmaxf(m_run, mc);
    const float alpha = __expf(m_run - mnew);
    float lc = 0.f;
    float p[4][4];
#pragma unroll
    for (int t = 0; t < 4; ++t)
#pragma unroll
      for (int r = 0; r < 4; ++r) {
        p[t][r] = __expf(sv[t][r] - mnew);
        lc += p[t][r];
      }
    lc += __shfl_xor(lc, 16);
    lc += __shfl_xor(lc, 32);
    l_run = l_run * alpha + lc;
    m_run = mnew;

    // P^T -> wave-private LDS scratch (lgkm-ordered; no barrier needed)
#pragma unroll
    for (int t = 0; t < 4; ++t) {
      *(unsigned int*)&myP[ln * 68 + t * 16 + quad * 4 + 0] = pk2(p[t][0], p[t][1]);
      *(unsigned int*)&myP[ln * 68 + t * 16 + quad * 4 + 2] = pk2(p[t][2], p[t][3]);
    }
#pragma unroll
    for (int ht = 0; ht < 8; ++ht)
#pragma unroll
      for (int r = 0; r < 4; ++r) oacc[ht][r] *= alpha;

    // O^T += V^T * P^T : 8 h-tiles x 2 kk = 16 MFMAs
#pragma unroll
    for (int kk2 = 0; kk2 < 2; ++kk2) {
      bf16x8 pf = *(bf16x8*)&myP[ln * 68 + kk2 * 32 + quad * 8];
#pragma unroll
      for (int ht = 0; ht < 8; ++ht) {
        const int hrow = ht * 16 + ln;
        bf16x8 vf = *(bf16x8*)&Vc[hrow * 64 + (((kk2 * 4 + quad) ^ (ln & 7)) * 8)];
        oacc[ht] = __builtin_amdgcn_mfma_f32_16x16x32_bf16(vf, pf, oacc[ht], 0, 0, 0);
      }
    }
  }

  // write partial: m, l per query; un-normalized O via LDS transpose
  if (quad == 0) {
    pm[(size_t)sid * 64 + wv * 16 + ln] = m_run;
    pl[(size_t)sid * 64 + wv * 16 + ln] = l_run;
  }
  __syncthreads();  // Ks/Vt dead; reuse for Ot
  float* Ot = (float*)smem;  // [64][132] f32 = 33.8 KB
#pragma unroll
  for (int ht = 0; ht < 8; ++ht)
    *(f32x4*)&Ot[(wv * 16 + ln) * 132 + ht * 16 + quad * 4] = oacc[ht];
  __syncthreads();
  float* dst = po + (size_t)sid * 8192;
#pragma unroll
  for (int i = 0; i < 8; ++i) {
    int slot2 = tid + i * 256;            // 2048 float4 slots: 64 q x 32
    int r2 = slot2 >> 5, c2 = slot2 & 31;
    *(f32x4*)(dst + r2 * 128 + c2 * 4) = *(f32x4*)&Ot[r2 * 132 + c2 * 4];
  }
}

// ---------------------------------------------------------------------------
// Attention part 2: combine <=4 partials per (b, 64q-tile) with max-rescale.
// 256 blocks x 256 thr; thread -> (q = tid>>2, 32 h-dims).
// ---------------------------------------------------------------------------
__global__ __launch_bounds__(256) void attn_reduce(
    const float* __restrict__ po, const float* __restrict__ pm,
    const float* __restrict__ pl, float* __restrict__ out) {
  const int b = blockIdx.x >> 5;
  const int j = blockIdx.x & 31;
  const int g = j >> 3;
  const int nseg = g + 1;
  const int sid0 = b * 80 + 4 * g * (g + 1) + (j - 8 * g) * nseg;
  const int tid = threadIdx.x;
  const int q = tid >> 2, hq = tid & 3;

  float m[4], l[4], a[4];
  float M = -INFINITY;
  for (int s2 = 0; s2 < nseg; ++s2) {
    m[s2] = pm[(size_t)(sid0 + s2) * 64 + q];
    l[s2] = pl[(size_t)(sid0 + s2) * 64 + q];
    M = fmaxf(M, m[s2]);
  }
  float lsum = 0.f;
  for (int s2 = 0; s2 < nseg; ++s2) {
    a[s2] = __expf(m[s2] - M);
    lsum += a[s2] * l[s2];
  }
  f32x4 acc[8];
#pragma unroll
  for (int i = 0; i < 8; ++i) acc[i] = (f32x4){0.f, 0.f, 0.f, 0.f};
  for (int s2 = 0; s2 < nseg; ++s2) {
    const float* src = po + (size_t)(sid0 + s2) * 8192 + q * 128 + hq * 32;
    const float as = a[s2];
#pragma unroll
    for (int i = 0; i < 8; ++i) {
      f32x4 v = *(const f32x4*)(src + i * 4);
#pragma unroll
      for (int c = 0; c < 4; ++c) acc[i][c] += as * v[c];
    }
  }
  const float inv = 1.0f / lsum;
  float* o = out + ((size_t)(b * T_ + j * 64 + q)) * H_ + hq * 32;
#pragma unroll
  for (int i = 0; i < 8; ++i) {
    f32x4 v;
#pragma unroll
    for (int c = 0; c < 4; ++c) v[c] = acc[i][c] * inv;
    *(f32x4*)(o + i * 4) = v;
  }
}

// ---------------------------------------------------------------------------
extern "C" void kernel_launch(void* const* d_in, const int* in_sizes, int n_in,
                              void* d_out, int out_size, void* d_ws, size_t ws_size,
                              hipStream_t stream) {
  const float* x  = (const float*)d_in[0];
  const float* Wq = (const float*)d_in[1];
  const float* Wk = (const float*)d_in[2];
  const float* Wv = (const float*)d_in[3];
  float* out = (float*)d_out;

  char* ws = (char*)d_ws;
  short* qb  = (short*)(ws);                // 4 MB   q  bf16 [BT][128]
  short* kb  = (short*)(ws + 4194304);      // 4 MB   k  bf16 [BT][128]
  short* vtb = (short*)(ws + 8388608);      // 4 MB   v^T bf16 [B][128][T]
  short* Wt  = (short*)(ws + 12582912);     // 0.75 MB W^T bf16 [3][128][1024]
  float* po  = (float*)(ws + 14680064);     // 20 MB  partial O (640 x 32 KB)
  float* pm  = (float*)(ws + 35651584);     // 160 KB partial m
  float* pl  = (float*)(ws + 35915776);     // 160 KB partial l

  wcvt_kernel<<<dim3(D_ / 64, 3), 256, 0, stream>>>(Wq, Wk, Wv, Wt);
  proj_kernel<<<dim3(BT / 64, 3), 256, 0, stream>>>(x, Wt, qb, kb, vtb);
  attn_part<<<dim3(8 * 80), 256, 0, stream>>>(qb, kb, vtb, po, pm, pl);
  attn_reduce<<<dim3(8 * 32), 256, 0, stream>>>(po, pm, pl, out);
}